// Round 2
// baseline (2180.676 us; speedup 1.0000x reference)
//
#include <hip/hip_runtime.h>
#include <math.h>

#define CDIM 512
#define LV 196
#define BV 64
#define BT 32
#define NW 24
#define NKEEP 98
#define NNON 98      // LV - NKEEP
#define KEEPED 49
#define HID 102
#define LAMBDA_ 4.0f
#define LN_EPS_ 1e-5f

// ws layout (float offsets)
#define WS_CAPNORM 0
#define WS_CAPGLO  (WS_CAPNORM + BT*NW*CDIM)     // 393216
#define WS_IMGGLO  (WS_CAPGLO + BT*CDIM)         // +16384
#define WS_INVN    (WS_IMGGLO + BV*CDIM)         // +32768
#define WS_WLOG    (WS_INVN + BV*LV)             // +12544
#define WS_SCORE   (WS_WLOG + BV*LV*KEEPED)      // +614656
// total = 1470976 floats = 5.88 MB

// ---------------------------------------------------------------------------
// K1: cap_norm, cap_glo (blocks 0..31), img_glo (blocks 32..95). 256 thr.
// ---------------------------------------------------------------------------
__global__ __launch_bounds__(256) void k1_glo(const float* __restrict__ img,
                                              const float* __restrict__ cap,
                                              float* __restrict__ ws) {
  __shared__ float red[256];
  int b = blockIdx.x, tid = threadIdx.x;
  int c0 = tid, c1 = tid + 256;
  if (b < BT) {
    int t = b;
    float s0 = 0.f, s1 = 0.f;
    for (int w = 0; w < NW; ++w) {
      const float* p = cap + ((size_t)t * NW + w) * CDIM;
      float x0 = p[c0], x1 = p[c1];
      red[tid] = x0 * x0 + x1 * x1;
      __syncthreads();
      for (int off = 128; off > 0; off >>= 1) {
        if (tid < off) red[tid] += red[tid + off];
        __syncthreads();
      }
      float inv = 1.f / fmaxf(sqrtf(red[0]), 1e-12f);
      __syncthreads();
      float* q = ws + WS_CAPNORM + ((size_t)t * NW + w) * CDIM;
      q[c0] = x0 * inv; q[c1] = x1 * inv;
      s0 += x0; s1 += x1;
    }
    float g0 = s0 / (float)NW, g1 = s1 / (float)NW;
    red[tid] = g0 * g0 + g1 * g1;
    __syncthreads();
    for (int off = 128; off > 0; off >>= 1) {
      if (tid < off) red[tid] += red[tid + off];
      __syncthreads();
    }
    float inv = 1.f / fmaxf(sqrtf(red[0]), 1e-12f);
    float* q = ws + WS_CAPGLO + (size_t)t * CDIM;
    q[c0] = g0 * inv; q[c1] = g1 * inv;
  } else {
    int v = b - BT;
    float s0 = 0.f, s1 = 0.f;
    const float* base = img + (size_t)v * LV * CDIM;
    for (int l = 0; l < LV; ++l) { s0 += base[l * CDIM + c0]; s1 += base[l * CDIM + c1]; }
    float g0 = s0 / (float)LV, g1 = s1 / (float)LV;
    red[tid] = g0 * g0 + g1 * g1;
    __syncthreads();
    for (int off = 128; off > 0; off >>= 1) {
      if (tid < off) red[tid] += red[tid + off];
      __syncthreads();
    }
    float inv = 1.f / fmaxf(sqrtf(red[0]), 1e-12f);
    float* q = ws + WS_IMGGLO + (size_t)v * CDIM;
    q[c0] = g0 * inv; q[c1] = g1 * inv;
  }
}

// ---------------------------------------------------------------------------
// K2: per img token: inv_norm, LN, MLP(gelu) -> wlog (49 logits/token).
// grid (64, 25), 256 thr, 8 tokens per block. W1 tiled through LDS.
// ---------------------------------------------------------------------------
#define TOK 8
__global__ __launch_bounds__(256) void k2_token(
    const float* __restrict__ img, const float* __restrict__ gamma,
    const float* __restrict__ beta, const float* __restrict__ W1,
    const float* __restrict__ b1, const float* __restrict__ W2,
    const float* __restrict__ b2, float* __restrict__ ws) {
  __shared__ float raw[TOK * CDIM];      // 16 KB
  __shared__ float xn[TOK * CDIM];       // 16 KB
  __shared__ float w1t[64 * HID];        // 25.5 KB
  __shared__ float hbuf[TOK * HID];      // 3.2 KB
  __shared__ float st_mean[TOK], st_rstd[TOK], st_invn[TOK];

  int v = blockIdx.x;
  int l0 = blockIdx.y * TOK;
  int tid = threadIdx.x;
  int nval = LV - l0; if (nval > TOK) nval = TOK; if (nval < 0) nval = 0;
  int wv = tid >> 6, lane = tid & 63;

  for (int i = tid; i < TOK * CDIM; i += 256) {
    int tok = i >> 9;
    raw[i] = (tok < nval) ? img[((size_t)v * LV + l0 + tok) * CDIM + (i & (CDIM - 1))] : 0.f;
  }
  __syncthreads();
  for (int tok = wv * 2; tok < wv * 2 + 2; ++tok) {
    float s = 0.f, sq = 0.f;
    #pragma unroll
    for (int j = 0; j < 8; ++j) { float x = raw[tok * CDIM + lane + 64 * j]; s += x; sq += x * x; }
    #pragma unroll
    for (int off = 32; off > 0; off >>= 1) { s += __shfl_xor(s, off, 64); sq += __shfl_xor(sq, off, 64); }
    if (lane == 0) {
      float mean = s / (float)CDIM;
      float var = sq / (float)CDIM - mean * mean;
      st_mean[tok] = mean;
      st_rstd[tok] = 1.f / sqrtf(var + LN_EPS_);
      st_invn[tok] = 1.f / fmaxf(sqrtf(sq), 1e-12f);
    }
  }
  __syncthreads();
  if (tid < nval) ws[WS_INVN + (size_t)v * LV + l0 + tid] = st_invn[tid];
  for (int i = tid; i < TOK * CDIM; i += 256) {
    int tok = i >> 9, c = i & (CDIM - 1);
    xn[i] = (raw[i] - st_mean[tok]) * st_rstd[tok] * gamma[c] + beta[c];
  }
  __syncthreads();

  // GEMM1: (8 tok x 512) @ (512 x 102), outputs 816, 4 per thread
  float acc1[4];
  int hh[4], tt[4]; bool av[4];
  #pragma unroll
  for (int s = 0; s < 4; ++s) {
    int oi = tid + 256 * s;
    av[s] = oi < TOK * HID;
    hh[s] = av[s] ? (oi % HID) : 0;
    tt[s] = av[s] ? (oi / HID) : 0;
    acc1[s] = av[s] ? b1[hh[s]] : 0.f;
  }
  for (int ct = 0; ct < 8; ++ct) {
    for (int i = tid; i < 64 * HID; i += 256) w1t[i] = W1[ct * 64 * HID + i];
    __syncthreads();
    for (int cc = 0; cc < 64; ++cc) {
      #pragma unroll
      for (int s = 0; s < 4; ++s)
        acc1[s] += xn[tt[s] * CDIM + ct * 64 + cc] * w1t[cc * HID + hh[s]];
    }
    __syncthreads();
  }
  #pragma unroll
  for (int s = 0; s < 4; ++s) {
    if (av[s]) {
      float x = acc1[s];
      float g = 0.5f * x * (1.f + erff(x * 0.70710678118654752f));
      hbuf[tid + 256 * s] = g;   // hbuf[tok*HID + h] == hbuf[oi]
    }
  }
  __syncthreads();

  // GEMM2: (8 tok x 102) @ (102 x 49) + b2 -> wlog
  #pragma unroll
  for (int s = 0; s < 2; ++s) {
    int oi = tid + 256 * s;
    if (oi < TOK * KEEPED) {
      int p = oi % KEEPED, tok = oi / KEEPED;
      float a = b2[p];
      for (int h2 = 0; h2 < HID; ++h2) a += hbuf[tok * HID + h2] * W2[h2 * KEEPED + p];
      if (tok < nval)
        ws[WS_WLOG + ((size_t)v * LV + l0 + tok) * KEEPED + p] = a;
    }
  }
}

// ---------------------------------------------------------------------------
// K3: scores. 33 queries (32 cap_glo + img_glo[v]) x tokens. grid (64,4).
// score[t,v,l] = (cap_glo[t].x + img_glo[v].x) * invn[v,l]
// ---------------------------------------------------------------------------
__global__ __launch_bounds__(256) void k3_score(const float* __restrict__ img,
                                                float* __restrict__ ws) {
  __shared__ float qt[33 * 64];     // 8.25 KB
  __shared__ float xt[64 * 65];     // 16.25 KB (padded)
  __shared__ float dself[64];
  int v = blockIdx.x;
  int t0 = blockIdx.y * 64;
  int tid = threadIdx.x;
  int tloc = tid & 63, qg = tid >> 6;
  float acc[9];
  #pragma unroll
  for (int i = 0; i < 9; ++i) acc[i] = 0.f;
  const float* capglo = ws + WS_CAPGLO;
  const float* imgglo = ws + WS_IMGGLO + (size_t)v * CDIM;

  for (int ct = 0; ct < 8; ++ct) {
    for (int i = tid; i < 33 * 64; i += 256) {
      int q = i >> 6, cc = i & 63;
      qt[i] = (q < 32) ? capglo[(size_t)q * CDIM + ct * 64 + cc] : imgglo[ct * 64 + cc];
    }
    for (int i = tid; i < 64 * 64; i += 256) {
      int tok = i >> 6, cc = i & 63;
      int l = t0 + tok;
      xt[tok * 65 + cc] = (l < LV) ? img[((size_t)v * LV + l) * CDIM + ct * 64 + cc] : 0.f;
    }
    __syncthreads();
    for (int cc = 0; cc < 64; ++cc) {
      float xv = xt[tloc * 65 + cc];
      #pragma unroll
      for (int qi = 0; qi < 9; ++qi) {
        int q = qg + 4 * qi;
        if (q < 33) acc[qi] += qt[q * 64 + cc] * xv;
      }
    }
    __syncthreads();
  }
  if (qg == 0) dself[tloc] = acc[8];  // q = 32
  __syncthreads();
  int l = t0 + tloc;
  if (l < LV) {
    float invn = ws[WS_INVN + (size_t)v * LV + l];
    float ds = dself[tloc];
    #pragma unroll
    for (int qi = 0; qi < 9; ++qi) {
      int q = qg + 4 * qi;
      if (q < 32) ws[WS_SCORE + ((size_t)q * BV + v) * LV + l] = (acc[qi] + ds) * invn;
    }
  }
}

// ---------------------------------------------------------------------------
// K4: per (t,v): rank/mask, extra token, pool softmax, aggr, l2norms,
// per-word attention + word_sim, mean. 2048 blocks x 1024 thr (16 waves).
// Channel mapping inside wave-channel phases: float4 idx = lane + 64*j2,
// i.e. channels 4*(lane+64*j2)+q — identity layout in s_sel, consistent
// across aggr / extra / l2norm / word phases.
// ---------------------------------------------------------------------------
__global__ __launch_bounds__(1024, 4) void k4_main(const float* __restrict__ img,
                                                   const float* __restrict__ scale_p,
                                                   const float* __restrict__ ws,
                                                   float* __restrict__ out) {
  __shared__ float s_sc[LV];
  __shared__ int   s_kidx[NKEEP];
  __shared__ int   s_nidx[NNON];
  __shared__ int   s_cnt[2];
  __shared__ float s_wk[NNON];
  __shared__ float s_w[KEEPED * NKEEP];   // 19.2 KB, [p][k]; also temp buffer
  __shared__ float s_sel[50 * CDIM];      // 100 KB, pools 0..48 aggr, 49 extra
  __shared__ float s_inv[50];
  __shared__ float s_red[128];

  int b = blockIdx.x;
  int v = b >> 5, t = b & 31;
  int tid = threadIdx.x;
  int wv = tid >> 6, lane = tid & 63;

  if (tid < 2) s_cnt[tid] = 0;
  if (tid < LV) s_sc[tid] = ws[WS_SCORE + ((size_t)t * BV + v) * LV + tid];
  __syncthreads();

  // --- rank & partition (stable argsort of -score semantics) ---
  if (tid < LV) {
    float my = s_sc[tid];
    int cnt = 0;
    for (int j = 0; j < LV; ++j) {
      float sj = s_sc[j];
      cnt += (sj > my) || (sj == my && j < tid);
    }
    bool keep = cnt < NKEEP;
    out[BV * BT + ((size_t)t * BV + v) * LV + tid] = keep ? 1.f : 0.f;
    if (keep) { int p = atomicAdd(&s_cnt[0], 1); s_kidx[p] = tid; }
    else      { int p = atomicAdd(&s_cnt[1], 1); s_nidx[p] = tid; }
  }
  __syncthreads();

  // --- softmax over non-kept scores ---
  if (tid < 128) s_red[tid] = (tid < NNON) ? s_sc[s_nidx[tid]] : -3.0e38f;
  __syncthreads();
  for (int off = 64; off > 0; off >>= 1) {
    if (tid < off) s_red[tid] = fmaxf(s_red[tid], s_red[tid + off]);
    __syncthreads();
  }
  float nm = s_red[0];
  __syncthreads();
  float e = 0.f;
  if (tid < NNON) e = expf(s_sc[s_nidx[tid]] - nm);
  if (tid < 128) s_red[tid] = e;
  __syncthreads();
  for (int off = 64; off > 0; off >>= 1) {
    if (tid < off) s_red[tid] += s_red[tid + off];
    __syncthreads();
  }
  float nS = s_red[0];
  __syncthreads();
  if (tid < NNON) s_wk[tid] = e / nS;
  __syncthreads();

  // --- extra token (pool 49): split k-range across two thread halves ---
  {
    int h = tid >> 9, c = tid & 511;
    float acc = 0.f;
    const float* base = img + (size_t)v * LV * CDIM + c;
    int k0 = h * 49;
    for (int k = k0; k < k0 + 49; ++k) acc += s_wk[k] * base[(size_t)s_nidx[k] * CDIM];
    s_w[h * 512 + c] = acc;   // temp use of s_w
  }
  __syncthreads();
  if (tid < 512) s_sel[49 * CDIM + tid] = s_w[tid] + s_w[512 + tid];
  __syncthreads();

  // --- pool logits: gather wlog of kept tokens, * scale ---
  float scale_val = scale_p[0];
  for (int i = tid; i < KEEPED * NKEEP; i += 1024) {
    int k = i / KEEPED, p = i - k * KEEPED;
    s_w[p * NKEEP + k] = ws[WS_WLOG + ((size_t)v * LV + s_kidx[k]) * KEEPED + p] * scale_val;
  }
  __syncthreads();

  // --- softmax over k per pool: 8-lane groups, 49*8 = 392 threads ---
  if (tid < KEEPED * 8) {
    int p = tid >> 3, g = tid & 7;
    float mm = -3e38f;
    for (int k = g; k < NKEEP; k += 8) mm = fmaxf(mm, s_w[p * NKEEP + k]);
    #pragma unroll
    for (int off = 4; off > 0; off >>= 1) mm = fmaxf(mm, __shfl_xor(mm, off, 8));
    float ss = 0.f;
    for (int k = g; k < NKEEP; k += 8) {
      float ee = expf(s_w[p * NKEEP + k] - mm);
      s_w[p * NKEEP + k] = ee;
      ss += ee;
    }
    #pragma unroll
    for (int off = 4; off > 0; off >>= 1) ss += __shfl_xor(ss, off, 8);
    float rs = 1.f / ss;
    for (int k = g; k < NKEEP; k += 8) s_w[p * NKEEP + k] *= rs;
  }
  __syncthreads();

  // --- aggr: wave wv owns pools {wv, wv+16, wv+32, wv+48}; float4 channels ---
  float4 acc4[4][2];
  #pragma unroll
  for (int i = 0; i < 4; ++i)
    #pragma unroll
    for (int j = 0; j < 2; ++j) acc4[i][j] = make_float4(0.f, 0.f, 0.f, 0.f);

  for (int k = 0; k < NKEEP; ++k) {
    const float4* row = (const float4*)(img + ((size_t)v * LV + s_kidx[k]) * CDIM);
    float4 tv0 = row[lane];
    float4 tv1 = row[lane + 64];
    #pragma unroll
    for (int i = 0; i < 4; ++i) {
      int p = wv + 16 * i;
      if (p < KEEPED) {
        float w = s_w[p * NKEEP + k];
        acc4[i][0].x += w * tv0.x; acc4[i][0].y += w * tv0.y;
        acc4[i][0].z += w * tv0.z; acc4[i][0].w += w * tv0.w;
        acc4[i][1].x += w * tv1.x; acc4[i][1].y += w * tv1.y;
        acc4[i][1].z += w * tv1.z; acc4[i][1].w += w * tv1.w;
      }
    }
  }
  #pragma unroll
  for (int i = 0; i < 4; ++i) {
    int p = wv + 16 * i;
    if (p < KEEPED) {
      float4* dst = (float4*)(s_sel + p * CDIM);
      dst[lane] = acc4[i][0];
      dst[lane + 64] = acc4[i][1];
    }
  }
  __syncthreads();

  // --- l2norm the 50 pools in place ---
  for (int p = wv; p < 50; p += 16) {
    const float4* src = (const float4*)(s_sel + p * CDIM);
    float4 a0 = src[lane], a1 = src[lane + 64];
    float ss = a0.x*a0.x + a0.y*a0.y + a0.z*a0.z + a0.w*a0.w
             + a1.x*a1.x + a1.y*a1.y + a1.z*a1.z + a1.w*a1.w;
    #pragma unroll
    for (int off = 32; off > 0; off >>= 1) ss += __shfl_xor(ss, off, 64);
    if (lane == 0) s_inv[p] = 1.f / fmaxf(sqrtf(ss), 1e-12f);
  }
  __syncthreads();
  for (int i = tid; i < 50 * CDIM; i += 1024) s_sel[i] *= s_inv[i >> 9];
  __syncthreads();

  // --- per-word: sims -> softmax -> ctx -> l2norm -> word_sim; wave/word ---
  float wsum = 0.f;
  const float* capb = ws + WS_CAPNORM + (size_t)t * NW * CDIM;
  for (int w = wv; w < NW; w += 16) {
    const float4* cap4 = (const float4*)(capb + (size_t)w * CDIM);
    float4 cv0 = cap4[lane], cv1 = cap4[lane + 64];
    float mylogit = -3e38f;
    float simmax = -3e38f;
    for (int p = 0; p < 50; ++p) {
      const float4* sp = (const float4*)(s_sel + p * CDIM);
      float4 s0 = sp[lane], s1 = sp[lane + 64];
      float s = cv0.x*s0.x + cv0.y*s0.y + cv0.z*s0.z + cv0.w*s0.w
              + cv1.x*s1.x + cv1.y*s1.y + cv1.z*s1.z + cv1.w*s1.w;
      #pragma unroll
      for (int off = 32; off > 0; off >>= 1) s += __shfl_xor(s, off, 64);
      float lg = LAMBDA_ * s;
      if (lane == p) mylogit = lg;
      simmax = fmaxf(simmax, lg);
    }
    float ee = (lane < 50) ? expf(mylogit - simmax) : 0.f;
    float d = ee;
    #pragma unroll
    for (int off = 32; off > 0; off >>= 1) d += __shfl_xor(d, off, 64);
    float attn = ee / d;
    float4 ctx0 = make_float4(0.f, 0.f, 0.f, 0.f);
    float4 ctx1 = make_float4(0.f, 0.f, 0.f, 0.f);
    for (int p = 0; p < 50; ++p) {
      float a = __shfl(attn, p, 64);
      const float4* sp = (const float4*)(s_sel + p * CDIM);
      float4 s0 = sp[lane], s1 = sp[lane + 64];
      ctx0.x += a * s0.x; ctx0.y += a * s0.y; ctx0.z += a * s0.z; ctx0.w += a * s0.w;
      ctx1.x += a * s1.x; ctx1.y += a * s1.y; ctx1.z += a * s1.z; ctx1.w += a * s1.w;
    }
    float ss = ctx0.x*ctx0.x + ctx0.y*ctx0.y + ctx0.z*ctx0.z + ctx0.w*ctx0.w
             + ctx1.x*ctx1.x + ctx1.y*ctx1.y + ctx1.z*ctx1.z + ctx1.w*ctx1.w;
    float cw = ctx0.x*cv0.x + ctx0.y*cv0.y + ctx0.z*cv0.z + ctx0.w*cv0.w
             + ctx1.x*cv1.x + ctx1.y*cv1.y + ctx1.z*cv1.z + ctx1.w*cv1.w;
    #pragma unroll
    for (int off = 32; off > 0; off >>= 1) { ss += __shfl_xor(ss, off, 64); cw += __shfl_xor(cw, off, 64); }
    float invc = 1.f / fmaxf(sqrtf(ss), 1e-12f);
    wsum += cw * invc;
  }
  if (lane == 0) s_red[wv] = wsum;
  __syncthreads();
  if (tid == 0) {
    float s = 0.f;
    #pragma unroll
    for (int i = 0; i < 16; ++i) s += s_red[i];
    out[(size_t)v * BT + t] = s / (float)NW;   // improve_sims = sim.T
  }
}

// ---------------------------------------------------------------------------
extern "C" void kernel_launch(void* const* d_in, const int* in_sizes, int n_in,
                              void* d_out, int out_size, void* d_ws, size_t ws_size,
                              hipStream_t stream) {
  const float* img   = (const float*)d_in[0];
  const float* cap   = (const float*)d_in[1];
  // d_in[2] = cap_lens (unused by forward)
  const float* gamma = (const float*)d_in[3];
  const float* beta  = (const float*)d_in[4];
  const float* W1    = (const float*)d_in[5];
  const float* b1    = (const float*)d_in[6];
  const float* W2    = (const float*)d_in[7];
  const float* b2    = (const float*)d_in[8];
  const float* scale = (const float*)d_in[9];
  float* ws  = (float*)d_ws;
  float* out = (float*)d_out;

  k1_glo <<<dim3(BT + BV), dim3(256), 0, stream>>>(img, cap, ws);
  k2_token<<<dim3(BV, (LV + TOK - 1) / TOK), dim3(256), 0, stream>>>(img, gamma, beta, W1, b1, W2, b2, ws);
  k3_score<<<dim3(BV, 4), dim3(256), 0, stream>>>(img, ws);
  k4_main <<<dim3(BV * BT), dim3(1024), 0, stream>>>(img, scale, ws, out);
}

// Round 3
// 2117.710 us; speedup vs baseline: 1.0297x; 1.0297x over previous
//
#include <hip/hip_runtime.h>
#include <math.h>

#define CDIM 512
#define LV 196
#define BV 64
#define BT 32
#define NW 24
#define NKEEP 98
#define NNON 98      // LV - NKEEP
#define KEEPED 49
#define HID 102
#define LAMBDA_ 4.0f
#define LN_EPS_ 1e-5f

// ws layout (float offsets)
#define WS_CAPNORM 0
#define WS_CAPGLO  (WS_CAPNORM + BT*NW*CDIM)     // 393216
#define WS_IMGGLO  (WS_CAPGLO + BT*CDIM)         // +16384
#define WS_INVN    (WS_IMGGLO + BV*CDIM)         // +32768
#define WS_WLOG    (WS_INVN + BV*LV)             // +12544
#define WS_SCORE   (WS_WLOG + BV*LV*KEEPED)      // +614656
// total = 1470976 floats = 5.88 MB

// ---------------------------------------------------------------------------
// K1: cap_norm, cap_glo (blocks 0..31), img_glo (blocks 32..95). 256 thr.
// ---------------------------------------------------------------------------
__global__ __launch_bounds__(256) void k1_glo(const float* __restrict__ img,
                                              const float* __restrict__ cap,
                                              float* __restrict__ ws) {
  __shared__ float red[256];
  int b = blockIdx.x, tid = threadIdx.x;
  int c0 = tid, c1 = tid + 256;
  if (b < BT) {
    int t = b;
    float s0 = 0.f, s1 = 0.f;
    for (int w = 0; w < NW; ++w) {
      const float* p = cap + ((size_t)t * NW + w) * CDIM;
      float x0 = p[c0], x1 = p[c1];
      red[tid] = x0 * x0 + x1 * x1;
      __syncthreads();
      for (int off = 128; off > 0; off >>= 1) {
        if (tid < off) red[tid] += red[tid + off];
        __syncthreads();
      }
      float inv = 1.f / fmaxf(sqrtf(red[0]), 1e-12f);
      __syncthreads();
      float* q = ws + WS_CAPNORM + ((size_t)t * NW + w) * CDIM;
      q[c0] = x0 * inv; q[c1] = x1 * inv;
      s0 += x0; s1 += x1;
    }
    float g0 = s0 / (float)NW, g1 = s1 / (float)NW;
    red[tid] = g0 * g0 + g1 * g1;
    __syncthreads();
    for (int off = 128; off > 0; off >>= 1) {
      if (tid < off) red[tid] += red[tid + off];
      __syncthreads();
    }
    float inv = 1.f / fmaxf(sqrtf(red[0]), 1e-12f);
    float* q = ws + WS_CAPGLO + (size_t)t * CDIM;
    q[c0] = g0 * inv; q[c1] = g1 * inv;
  } else {
    int v = b - BT;
    float s0 = 0.f, s1 = 0.f;
    const float* base = img + (size_t)v * LV * CDIM;
    for (int l = 0; l < LV; ++l) { s0 += base[l * CDIM + c0]; s1 += base[l * CDIM + c1]; }
    float g0 = s0 / (float)LV, g1 = s1 / (float)LV;
    red[tid] = g0 * g0 + g1 * g1;
    __syncthreads();
    for (int off = 128; off > 0; off >>= 1) {
      if (tid < off) red[tid] += red[tid + off];
      __syncthreads();
    }
    float inv = 1.f / fmaxf(sqrtf(red[0]), 1e-12f);
    float* q = ws + WS_IMGGLO + (size_t)v * CDIM;
    q[c0] = g0 * inv; q[c1] = g1 * inv;
  }
}

// ---------------------------------------------------------------------------
// K2: per img token: inv_norm, LN, MLP(gelu) -> wlog (49 logits/token).
// grid (64, 25), 256 thr, 8 tokens per block. W1 tiled through LDS.
// ---------------------------------------------------------------------------
#define TOK 8
__global__ __launch_bounds__(256) void k2_token(
    const float* __restrict__ img, const float* __restrict__ gamma,
    const float* __restrict__ beta, const float* __restrict__ W1,
    const float* __restrict__ b1, const float* __restrict__ W2,
    const float* __restrict__ b2, float* __restrict__ ws) {
  __shared__ float raw[TOK * CDIM];      // 16 KB
  __shared__ float xn[TOK * CDIM];       // 16 KB
  __shared__ float w1t[64 * HID];        // 25.5 KB
  __shared__ float hbuf[TOK * HID];      // 3.2 KB
  __shared__ float st_mean[TOK], st_rstd[TOK], st_invn[TOK];

  int v = blockIdx.x;
  int l0 = blockIdx.y * TOK;
  int tid = threadIdx.x;
  int nval = LV - l0; if (nval > TOK) nval = TOK; if (nval < 0) nval = 0;
  int wv = tid >> 6, lane = tid & 63;

  for (int i = tid; i < TOK * CDIM; i += 256) {
    int tok = i >> 9;
    raw[i] = (tok < nval) ? img[((size_t)v * LV + l0 + tok) * CDIM + (i & (CDIM - 1))] : 0.f;
  }
  __syncthreads();
  for (int tok = wv * 2; tok < wv * 2 + 2; ++tok) {
    float s = 0.f, sq = 0.f;
    #pragma unroll
    for (int j = 0; j < 8; ++j) { float x = raw[tok * CDIM + lane + 64 * j]; s += x; sq += x * x; }
    #pragma unroll
    for (int off = 32; off > 0; off >>= 1) { s += __shfl_xor(s, off, 64); sq += __shfl_xor(sq, off, 64); }
    if (lane == 0) {
      float mean = s / (float)CDIM;
      float var = sq / (float)CDIM - mean * mean;
      st_mean[tok] = mean;
      st_rstd[tok] = 1.f / sqrtf(var + LN_EPS_);
      st_invn[tok] = 1.f / fmaxf(sqrtf(sq), 1e-12f);
    }
  }
  __syncthreads();
  if (tid < nval) ws[WS_INVN + (size_t)v * LV + l0 + tid] = st_invn[tid];
  for (int i = tid; i < TOK * CDIM; i += 256) {
    int tok = i >> 9, c = i & (CDIM - 1);
    xn[i] = (raw[i] - st_mean[tok]) * st_rstd[tok] * gamma[c] + beta[c];
  }
  __syncthreads();

  // GEMM1: (8 tok x 512) @ (512 x 102), outputs 816, 4 per thread
  float acc1[4];
  int hh[4], tt[4]; bool av[4];
  #pragma unroll
  for (int s = 0; s < 4; ++s) {
    int oi = tid + 256 * s;
    av[s] = oi < TOK * HID;
    hh[s] = av[s] ? (oi % HID) : 0;
    tt[s] = av[s] ? (oi / HID) : 0;
    acc1[s] = av[s] ? b1[hh[s]] : 0.f;
  }
  for (int ct = 0; ct < 8; ++ct) {
    for (int i = tid; i < 64 * HID; i += 256) w1t[i] = W1[ct * 64 * HID + i];
    __syncthreads();
    for (int cc = 0; cc < 64; ++cc) {
      #pragma unroll
      for (int s = 0; s < 4; ++s)
        acc1[s] += xn[tt[s] * CDIM + ct * 64 + cc] * w1t[cc * HID + hh[s]];
    }
    __syncthreads();
  }
  #pragma unroll
  for (int s = 0; s < 4; ++s) {
    if (av[s]) {
      float x = acc1[s];
      float g = 0.5f * x * (1.f + erff(x * 0.70710678118654752f));
      hbuf[tid + 256 * s] = g;   // hbuf[tok*HID + h] == hbuf[oi]
    }
  }
  __syncthreads();

  // GEMM2: (8 tok x 102) @ (102 x 49) + b2 -> wlog
  #pragma unroll
  for (int s = 0; s < 2; ++s) {
    int oi = tid + 256 * s;
    if (oi < TOK * KEEPED) {
      int p = oi % KEEPED, tok = oi / KEEPED;
      float a = b2[p];
      for (int h2 = 0; h2 < HID; ++h2) a += hbuf[tok * HID + h2] * W2[h2 * KEEPED + p];
      if (tok < nval)
        ws[WS_WLOG + ((size_t)v * LV + l0 + tok) * KEEPED + p] = a;
    }
  }
}

// ---------------------------------------------------------------------------
// K3: scores. 33 queries (32 cap_glo + img_glo[v]) x tokens. grid (64,4).
// score[t,v,l] = (cap_glo[t].x + img_glo[v].x) * invn[v,l]
// ---------------------------------------------------------------------------
__global__ __launch_bounds__(256) void k3_score(const float* __restrict__ img,
                                                float* __restrict__ ws) {
  __shared__ float qt[33 * 64];     // 8.25 KB
  __shared__ float xt[64 * 65];     // 16.25 KB (padded)
  __shared__ float dself[64];
  int v = blockIdx.x;
  int t0 = blockIdx.y * 64;
  int tid = threadIdx.x;
  int tloc = tid & 63, qg = tid >> 6;
  float acc[9];
  #pragma unroll
  for (int i = 0; i < 9; ++i) acc[i] = 0.f;
  const float* capglo = ws + WS_CAPGLO;
  const float* imgglo = ws + WS_IMGGLO + (size_t)v * CDIM;

  for (int ct = 0; ct < 8; ++ct) {
    for (int i = tid; i < 33 * 64; i += 256) {
      int q = i >> 6, cc = i & 63;
      qt[i] = (q < 32) ? capglo[(size_t)q * CDIM + ct * 64 + cc] : imgglo[ct * 64 + cc];
    }
    for (int i = tid; i < 64 * 64; i += 256) {
      int tok = i >> 6, cc = i & 63;
      int l = t0 + tok;
      xt[tok * 65 + cc] = (l < LV) ? img[((size_t)v * LV + l) * CDIM + ct * 64 + cc] : 0.f;
    }
    __syncthreads();
    for (int cc = 0; cc < 64; ++cc) {
      float xv = xt[tloc * 65 + cc];
      #pragma unroll
      for (int qi = 0; qi < 9; ++qi) {
        int q = qg + 4 * qi;
        if (q < 33) acc[qi] += qt[q * 64 + cc] * xv;
      }
    }
    __syncthreads();
  }
  if (qg == 0) dself[tloc] = acc[8];  // q = 32
  __syncthreads();
  int l = t0 + tloc;
  if (l < LV) {
    float invn = ws[WS_INVN + (size_t)v * LV + l];
    float ds = dself[tloc];
    #pragma unroll
    for (int qi = 0; qi < 9; ++qi) {
      int q = qg + 4 * qi;
      if (q < 32) ws[WS_SCORE + ((size_t)q * BV + v) * LV + l] = (acc[qi] + ds) * invn;
    }
  }
}

// ---------------------------------------------------------------------------
// K4: per (t,v): rank/mask, extra token, pool softmax, aggr, l2norms,
// per-word attention + word_sim, mean. 2048 blocks x 1024 thr (16 waves).
// LDS: 153.5 KB -> 1 block/CU, 4 waves/EU. amdgpu_waves_per_eu(4,4) pins the
// register allocator to the 128-VGPR budget (R2 regression: allocator chased
// 8 waves/EU -> 64 VGPR -> 2.5 GB scratch spill).
// ---------------------------------------------------------------------------
__global__ __attribute__((amdgpu_waves_per_eu(4, 4)))
__launch_bounds__(1024) void k4_main(const float* __restrict__ img,
                                     const float* __restrict__ scale_p,
                                     const float* __restrict__ ws,
                                     float* __restrict__ out) {
  __shared__ float s_sc[LV];
  __shared__ int   s_kidx[NKEEP];
  __shared__ int   s_nidx[NNON];
  __shared__ int   s_cnt[2];
  __shared__ float s_wk[NNON];
  __shared__ float s_w[KEEPED * NKEEP];   // 19.2 KB, [p][k]; also temp buffer
  __shared__ float s_sel[50 * CDIM];      // 100 KB, pools 0..48 aggr, 49 extra
  __shared__ float s_tok[16 * CDIM];      // 32 KB kept-token staging
  __shared__ float s_inv[50];
  __shared__ float s_red[128];

  int b = blockIdx.x;
  int v = b >> 5, t = b & 31;
  int tid = threadIdx.x;
  int wv = tid >> 6, lane = tid & 63;

  if (tid < 2) s_cnt[tid] = 0;
  if (tid < LV) s_sc[tid] = ws[WS_SCORE + ((size_t)t * BV + v) * LV + tid];
  __syncthreads();

  // --- rank & partition (stable argsort of -score semantics) ---
  if (tid < LV) {
    float my = s_sc[tid];
    int cnt = 0;
    for (int j = 0; j < LV; ++j) {
      float sj = s_sc[j];
      cnt += (sj > my) || (sj == my && j < tid);
    }
    bool keep = cnt < NKEEP;
    out[BV * BT + ((size_t)t * BV + v) * LV + tid] = keep ? 1.f : 0.f;
    if (keep) { int p = atomicAdd(&s_cnt[0], 1); s_kidx[p] = tid; }
    else      { int p = atomicAdd(&s_cnt[1], 1); s_nidx[p] = tid; }
  }
  __syncthreads();

  // --- softmax over non-kept scores ---
  if (tid < 128) s_red[tid] = (tid < NNON) ? s_sc[s_nidx[tid]] : -3.0e38f;
  __syncthreads();
  for (int off = 64; off > 0; off >>= 1) {
    if (tid < off) s_red[tid] = fmaxf(s_red[tid], s_red[tid + off]);
    __syncthreads();
  }
  float nm = s_red[0];
  __syncthreads();
  float e = 0.f;
  if (tid < NNON) e = expf(s_sc[s_nidx[tid]] - nm);
  if (tid < 128) s_red[tid] = e;
  __syncthreads();
  for (int off = 64; off > 0; off >>= 1) {
    if (tid < off) s_red[tid] += s_red[tid + off];
    __syncthreads();
  }
  float nS = s_red[0];
  __syncthreads();
  if (tid < NNON) s_wk[tid] = e / nS;
  __syncthreads();

  // --- extra token (pool 49): split k-range across two thread halves ---
  {
    int h = tid >> 9, c = tid & 511;
    float acc = 0.f;
    const float* base = img + (size_t)v * LV * CDIM + c;
    int k0 = h * 49;
    for (int k = k0; k < k0 + 49; ++k) acc += s_wk[k] * base[(size_t)s_nidx[k] * CDIM];
    s_w[h * 512 + c] = acc;   // temp use of s_w
  }
  __syncthreads();
  if (tid < 512) s_sel[49 * CDIM + tid] = s_w[tid] + s_w[512 + tid];
  __syncthreads();

  // --- pool logits: gather wlog of kept tokens, * scale ---
  float scale_val = scale_p[0];
  for (int i = tid; i < KEEPED * NKEEP; i += 1024) {
    int k = i / KEEPED, p = i - k * KEEPED;
    s_w[p * NKEEP + k] = ws[WS_WLOG + ((size_t)v * LV + s_kidx[k]) * KEEPED + p] * scale_val;
  }
  __syncthreads();

  // --- softmax over k per pool: 8-lane groups, 49*8 = 392 threads ---
  if (tid < KEEPED * 8) {
    int p = tid >> 3, g = tid & 7;
    float mm = -3e38f;
    for (int k = g; k < NKEEP; k += 8) mm = fmaxf(mm, s_w[p * NKEEP + k]);
    #pragma unroll
    for (int off = 4; off > 0; off >>= 1) mm = fmaxf(mm, __shfl_xor(mm, off, 8));
    float ss = 0.f;
    for (int k = g; k < NKEEP; k += 8) {
      float ee = expf(s_w[p * NKEEP + k] - mm);
      s_w[p * NKEEP + k] = ee;
      ss += ee;
    }
    #pragma unroll
    for (int off = 4; off > 0; off >>= 1) ss += __shfl_xor(ss, off, 8);
    float rs = 1.f / ss;
    for (int k = g; k < NKEEP; k += 8) s_w[p * NKEEP + k] *= rs;
  }

  // --- aggr: stage kept rows in LDS (16 at a time), wave wv owns pools
  //     {wv, wv+16, wv+32, wv+48}; float4 channels ---
  float4 acc4[4][2];
  #pragma unroll
  for (int i = 0; i < 4; ++i)
    #pragma unroll
    for (int j = 0; j < 2; ++j) acc4[i][j] = make_float4(0.f, 0.f, 0.f, 0.f);

  float4* s_tok4 = (float4*)s_tok;
  for (int kt = 0; kt < NKEEP; kt += 16) {
    int kn = NKEEP - kt; if (kn > 16) kn = 16;
    __syncthreads();   // covers s_w softmax on first iter, prev compute after
    for (int i = tid; i < kn * 128; i += 1024) {
      int ko = i >> 7;
      const float4* row = (const float4*)(img + ((size_t)v * LV + s_kidx[kt + ko]) * CDIM);
      s_tok4[i] = row[i & 127];
    }
    __syncthreads();
    for (int ko = 0; ko < kn; ++ko) {
      int k = kt + ko;
      float4 tv0 = s_tok4[ko * 128 + lane];
      float4 tv1 = s_tok4[ko * 128 + 64 + lane];
      #pragma unroll
      for (int i = 0; i < 4; ++i) {
        int p = wv + 16 * i;
        if (p < KEEPED) {
          float w = s_w[p * NKEEP + k];
          acc4[i][0].x += w * tv0.x; acc4[i][0].y += w * tv0.y;
          acc4[i][0].z += w * tv0.z; acc4[i][0].w += w * tv0.w;
          acc4[i][1].x += w * tv1.x; acc4[i][1].y += w * tv1.y;
          acc4[i][1].z += w * tv1.z; acc4[i][1].w += w * tv1.w;
        }
      }
    }
  }
  #pragma unroll
  for (int i = 0; i < 4; ++i) {
    int p = wv + 16 * i;
    if (p < KEEPED) {
      float4* dst = (float4*)(s_sel + p * CDIM);
      dst[lane] = acc4[i][0];
      dst[lane + 64] = acc4[i][1];
    }
  }
  __syncthreads();

  // --- l2norm the 50 pools in place ---
  for (int p = wv; p < 50; p += 16) {
    const float4* src = (const float4*)(s_sel + p * CDIM);
    float4 a0 = src[lane], a1 = src[lane + 64];
    float ss = a0.x*a0.x + a0.y*a0.y + a0.z*a0.z + a0.w*a0.w
             + a1.x*a1.x + a1.y*a1.y + a1.z*a1.z + a1.w*a1.w;
    #pragma unroll
    for (int off = 32; off > 0; off >>= 1) ss += __shfl_xor(ss, off, 64);
    if (lane == 0) s_inv[p] = 1.f / fmaxf(sqrtf(ss), 1e-12f);
  }
  __syncthreads();
  for (int i = tid; i < 50 * CDIM; i += 1024) s_sel[i] *= s_inv[i >> 9];
  __syncthreads();

  // --- per-word: sims -> softmax -> ctx -> l2norm -> word_sim; wave/word ---
  float wsum = 0.f;
  const float* capb = ws + WS_CAPNORM + (size_t)t * NW * CDIM;
  for (int w = wv; w < NW; w += 16) {
    const float4* cap4 = (const float4*)(capb + (size_t)w * CDIM);
    float4 cv0 = cap4[lane], cv1 = cap4[lane + 64];
    float mylogit = -3e38f;
    float simmax = -3e38f;
    for (int p = 0; p < 50; ++p) {
      const float4* sp = (const float4*)(s_sel + p * CDIM);
      float4 s0 = sp[lane], s1 = sp[lane + 64];
      float s = cv0.x*s0.x + cv0.y*s0.y + cv0.z*s0.z + cv0.w*s0.w
              + cv1.x*s1.x + cv1.y*s1.y + cv1.z*s1.z + cv1.w*s1.w;
      #pragma unroll
      for (int off = 32; off > 0; off >>= 1) s += __shfl_xor(s, off, 64);
      float lg = LAMBDA_ * s;
      if (lane == p) mylogit = lg;
      simmax = fmaxf(simmax, lg);
    }
    float ee = (lane < 50) ? expf(mylogit - simmax) : 0.f;
    float d = ee;
    #pragma unroll
    for (int off = 32; off > 0; off >>= 1) d += __shfl_xor(d, off, 64);
    float attn = ee / d;
    float4 ctx0 = make_float4(0.f, 0.f, 0.f, 0.f);
    float4 ctx1 = make_float4(0.f, 0.f, 0.f, 0.f);
    for (int p = 0; p < 50; ++p) {
      float a = __shfl(attn, p, 64);
      const float4* sp = (const float4*)(s_sel + p * CDIM);
      float4 s0 = sp[lane], s1 = sp[lane + 64];
      ctx0.x += a * s0.x; ctx0.y += a * s0.y; ctx0.z += a * s0.z; ctx0.w += a * s0.w;
      ctx1.x += a * s1.x; ctx1.y += a * s1.y; ctx1.z += a * s1.z; ctx1.w += a * s1.w;
    }
    float ss = ctx0.x*ctx0.x + ctx0.y*ctx0.y + ctx0.z*ctx0.z + ctx0.w*ctx0.w
             + ctx1.x*ctx1.x + ctx1.y*ctx1.y + ctx1.z*ctx1.z + ctx1.w*ctx1.w;
    float cw = ctx0.x*cv0.x + ctx0.y*cv0.y + ctx0.z*cv0.z + ctx0.w*cv0.w
             + ctx1.x*cv1.x + ctx1.y*cv1.y + ctx1.z*cv1.z + ctx1.w*cv1.w;
    #pragma unroll
    for (int off = 32; off > 0; off >>= 1) { ss += __shfl_xor(ss, off, 64); cw += __shfl_xor(cw, off, 64); }
    float invc = 1.f / fmaxf(sqrtf(ss), 1e-12f);
    wsum += cw * invc;
  }
  if (lane == 0) s_red[wv] = wsum;
  __syncthreads();
  if (tid == 0) {
    float s = 0.f;
    #pragma unroll
    for (int i = 0; i < 16; ++i) s += s_red[i];
    out[(size_t)v * BT + t] = s / (float)NW;   // improve_sims = sim.T
  }
}

// ---------------------------------------------------------------------------
extern "C" void kernel_launch(void* const* d_in, const int* in_sizes, int n_in,
                              void* d_out, int out_size, void* d_ws, size_t ws_size,
                              hipStream_t stream) {
  const float* img   = (const float*)d_in[0];
  const float* cap   = (const float*)d_in[1];
  // d_in[2] = cap_lens (unused by forward)
  const float* gamma = (const float*)d_in[3];
  const float* beta  = (const float*)d_in[4];
  const float* W1    = (const float*)d_in[5];
  const float* b1    = (const float*)d_in[6];
  const float* W2    = (const float*)d_in[7];
  const float* b2    = (const float*)d_in[8];
  const float* scale = (const float*)d_in[9];
  float* ws  = (float*)d_ws;
  float* out = (float*)d_out;

  k1_glo <<<dim3(BT + BV), dim3(256), 0, stream>>>(img, cap, ws);
  k2_token<<<dim3(BV, (LV + TOK - 1) / TOK), dim3(256), 0, stream>>>(img, gamma, beta, W1, b1, W2, b2, ws);
  k3_score<<<dim3(BV, 4), dim3(256), 0, stream>>>(img, ws);
  k4_main <<<dim3(BV * BT), dim3(1024), 0, stream>>>(img, scale, ws, out);
}

// Round 4
// 832.197 us; speedup vs baseline: 2.6204x; 2.5447x over previous
//
#include <hip/hip_runtime.h>
#include <hip/hip_bf16.h>
#include <math.h>

#define CDIM 512
#define LV 196
#define BV 64
#define BT 32
#define NW 24
#define NKEEP 98
#define NNON 98      // LV - NKEEP
#define KEEPED 49
#define HID 102
#define LAMBDA_ 4.0f
#define LN_EPS_ 1e-5f

// ws layout (float offsets)
#define WS_CAPNORM 0
#define WS_CAPGLO  (WS_CAPNORM + BT*NW*CDIM)     // 393216
#define WS_IMGGLO  (WS_CAPGLO + BT*CDIM)         // +16384
#define WS_INVN    (WS_IMGGLO + BV*CDIM)         // +32768
#define WS_WLOG    (WS_INVN + BV*LV)             // +12544
#define WS_SCORE   (WS_WLOG + BV*LV*KEEPED)      // +614656
// total = 1470976 floats = 5.88 MB

// ---------------------------------------------------------------------------
// K1: cap_norm, cap_glo (blocks 0..31), img_glo (blocks 32..95). 256 thr.
// ---------------------------------------------------------------------------
__global__ __launch_bounds__(256) void k1_glo(const float* __restrict__ img,
                                              const float* __restrict__ cap,
                                              float* __restrict__ ws) {
  __shared__ float red[256];
  int b = blockIdx.x, tid = threadIdx.x;
  int c0 = tid, c1 = tid + 256;
  if (b < BT) {
    int t = b;
    float s0 = 0.f, s1 = 0.f;
    for (int w = 0; w < NW; ++w) {
      const float* p = cap + ((size_t)t * NW + w) * CDIM;
      float x0 = p[c0], x1 = p[c1];
      red[tid] = x0 * x0 + x1 * x1;
      __syncthreads();
      for (int off = 128; off > 0; off >>= 1) {
        if (tid < off) red[tid] += red[tid + off];
        __syncthreads();
      }
      float inv = 1.f / fmaxf(sqrtf(red[0]), 1e-12f);
      __syncthreads();
      float* q = ws + WS_CAPNORM + ((size_t)t * NW + w) * CDIM;
      q[c0] = x0 * inv; q[c1] = x1 * inv;
      s0 += x0; s1 += x1;
    }
    float g0 = s0 / (float)NW, g1 = s1 / (float)NW;
    red[tid] = g0 * g0 + g1 * g1;
    __syncthreads();
    for (int off = 128; off > 0; off >>= 1) {
      if (tid < off) red[tid] += red[tid + off];
      __syncthreads();
    }
    float inv = 1.f / fmaxf(sqrtf(red[0]), 1e-12f);
    float* q = ws + WS_CAPGLO + (size_t)t * CDIM;
    q[c0] = g0 * inv; q[c1] = g1 * inv;
  } else {
    int v = b - BT;
    float s0 = 0.f, s1 = 0.f;
    const float* base = img + (size_t)v * LV * CDIM;
    for (int l = 0; l < LV; ++l) { s0 += base[l * CDIM + c0]; s1 += base[l * CDIM + c1]; }
    float g0 = s0 / (float)LV, g1 = s1 / (float)LV;
    red[tid] = g0 * g0 + g1 * g1;
    __syncthreads();
    for (int off = 128; off > 0; off >>= 1) {
      if (tid < off) red[tid] += red[tid + off];
      __syncthreads();
    }
    float inv = 1.f / fmaxf(sqrtf(red[0]), 1e-12f);
    float* q = ws + WS_IMGGLO + (size_t)v * CDIM;
    q[c0] = g0 * inv; q[c1] = g1 * inv;
  }
}

// ---------------------------------------------------------------------------
// K2: per img token: inv_norm, LN, MLP(gelu) -> wlog (49 logits/token).
// grid (64, 25), 256 thr, 8 tokens per block. W1 tiled through LDS.
// ---------------------------------------------------------------------------
#define TOK 8
__global__ __launch_bounds__(256) void k2_token(
    const float* __restrict__ img, const float* __restrict__ gamma,
    const float* __restrict__ beta, const float* __restrict__ W1,
    const float* __restrict__ b1, const float* __restrict__ W2,
    const float* __restrict__ b2, float* __restrict__ ws) {
  __shared__ float raw[TOK * CDIM];      // 16 KB
  __shared__ float xn[TOK * CDIM];       // 16 KB
  __shared__ float w1t[64 * HID];        // 25.5 KB
  __shared__ float hbuf[TOK * HID];      // 3.2 KB
  __shared__ float st_mean[TOK], st_rstd[TOK], st_invn[TOK];

  int v = blockIdx.x;
  int l0 = blockIdx.y * TOK;
  int tid = threadIdx.x;
  int nval = LV - l0; if (nval > TOK) nval = TOK; if (nval < 0) nval = 0;
  int wv = tid >> 6, lane = tid & 63;

  for (int i = tid; i < TOK * CDIM; i += 256) {
    int tok = i >> 9;
    raw[i] = (tok < nval) ? img[((size_t)v * LV + l0 + tok) * CDIM + (i & (CDIM - 1))] : 0.f;
  }
  __syncthreads();
  for (int tok = wv * 2; tok < wv * 2 + 2; ++tok) {
    float s = 0.f, sq = 0.f;
    #pragma unroll
    for (int j = 0; j < 8; ++j) { float x = raw[tok * CDIM + lane + 64 * j]; s += x; sq += x * x; }
    #pragma unroll
    for (int off = 32; off > 0; off >>= 1) { s += __shfl_xor(s, off, 64); sq += __shfl_xor(sq, off, 64); }
    if (lane == 0) {
      float mean = s / (float)CDIM;
      float var = sq / (float)CDIM - mean * mean;
      st_mean[tok] = mean;
      st_rstd[tok] = 1.f / sqrtf(var + LN_EPS_);
      st_invn[tok] = 1.f / fmaxf(sqrtf(sq), 1e-12f);
    }
  }
  __syncthreads();
  if (tid < nval) ws[WS_INVN + (size_t)v * LV + l0 + tid] = st_invn[tid];
  for (int i = tid; i < TOK * CDIM; i += 256) {
    int tok = i >> 9, c = i & (CDIM - 1);
    xn[i] = (raw[i] - st_mean[tok]) * st_rstd[tok] * gamma[c] + beta[c];
  }
  __syncthreads();

  // GEMM1: (8 tok x 512) @ (512 x 102), outputs 816, 4 per thread
  float acc1[4];
  int hh[4], tt[4]; bool av[4];
  #pragma unroll
  for (int s = 0; s < 4; ++s) {
    int oi = tid + 256 * s;
    av[s] = oi < TOK * HID;
    hh[s] = av[s] ? (oi % HID) : 0;
    tt[s] = av[s] ? (oi / HID) : 0;
    acc1[s] = av[s] ? b1[hh[s]] : 0.f;
  }
  for (int ct = 0; ct < 8; ++ct) {
    for (int i = tid; i < 64 * HID; i += 256) w1t[i] = W1[ct * 64 * HID + i];
    __syncthreads();
    for (int cc = 0; cc < 64; ++cc) {
      #pragma unroll
      for (int s = 0; s < 4; ++s)
        acc1[s] += xn[tt[s] * CDIM + ct * 64 + cc] * w1t[cc * HID + hh[s]];
    }
    __syncthreads();
  }
  #pragma unroll
  for (int s = 0; s < 4; ++s) {
    if (av[s]) {
      float x = acc1[s];
      float g = 0.5f * x * (1.f + erff(x * 0.70710678118654752f));
      hbuf[tid + 256 * s] = g;   // hbuf[tok*HID + h] == hbuf[oi]
    }
  }
  __syncthreads();

  // GEMM2: (8 tok x 102) @ (102 x 49) + b2 -> wlog
  #pragma unroll
  for (int s = 0; s < 2; ++s) {
    int oi = tid + 256 * s;
    if (oi < TOK * KEEPED) {
      int p = oi % KEEPED, tok = oi / KEEPED;
      float a = b2[p];
      for (int h2 = 0; h2 < HID; ++h2) a += hbuf[tok * HID + h2] * W2[h2 * KEEPED + p];
      if (tok < nval)
        ws[WS_WLOG + ((size_t)v * LV + l0 + tok) * KEEPED + p] = a;
    }
  }
}

// ---------------------------------------------------------------------------
// K3: scores. 33 queries (32 cap_glo + img_glo[v]) x tokens. grid (64,4).
// ---------------------------------------------------------------------------
__global__ __launch_bounds__(256) void k3_score(const float* __restrict__ img,
                                                float* __restrict__ ws) {
  __shared__ float qt[33 * 64];     // 8.25 KB
  __shared__ float xt[64 * 65];     // 16.25 KB (padded)
  __shared__ float dself[64];
  int v = blockIdx.x;
  int t0 = blockIdx.y * 64;
  int tid = threadIdx.x;
  int tloc = tid & 63, qg = tid >> 6;
  float acc[9];
  #pragma unroll
  for (int i = 0; i < 9; ++i) acc[i] = 0.f;
  const float* capglo = ws + WS_CAPGLO;
  const float* imgglo = ws + WS_IMGGLO + (size_t)v * CDIM;

  for (int ct = 0; ct < 8; ++ct) {
    for (int i = tid; i < 33 * 64; i += 256) {
      int q = i >> 6, cc = i & 63;
      qt[i] = (q < 32) ? capglo[(size_t)q * CDIM + ct * 64 + cc] : imgglo[ct * 64 + cc];
    }
    for (int i = tid; i < 64 * 64; i += 256) {
      int tok = i >> 6, cc = i & 63;
      int l = t0 + tok;
      xt[tok * 65 + cc] = (l < LV) ? img[((size_t)v * LV + l) * CDIM + ct * 64 + cc] : 0.f;
    }
    __syncthreads();
    for (int cc = 0; cc < 64; ++cc) {
      float xv = xt[tloc * 65 + cc];
      #pragma unroll
      for (int qi = 0; qi < 9; ++qi) {
        int q = qg + 4 * qi;
        if (q < 33) acc[qi] += qt[q * 64 + cc] * xv;
      }
    }
    __syncthreads();
  }
  if (qg == 0) dself[tloc] = acc[8];  // q = 32
  __syncthreads();
  int l = t0 + tloc;
  if (l < LV) {
    float invn = ws[WS_INVN + (size_t)v * LV + l];
    float ds = dself[tloc];
    #pragma unroll
    for (int qi = 0; qi < 9; ++qi) {
      int q = qg + 4 * qi;
      if (q < 32) ws[WS_SCORE + ((size_t)q * BV + v) * LV + l] = (acc[qi] + ds) * invn;
    }
  }
}

// ---------------------------------------------------------------------------
// K4 redesign (R4): 512 threads (8 waves) -> compiler gives 128 VGPRs (R1
// evidence; 1024 thr forced 64 VGPR + spill). LDS ~71 KB -> 2 blocks/CU.
// Aggr K-loop is barrier-free (direct global reads of L2-resident img rows)
// so the 56-float accumulator never crosses a barrier -> no spill.
// sel pools stored bf16 in LDS (halves footprint; ~0.2% rel err, ok vs 2e-2).
// ---------------------------------------------------------------------------
__device__ __forceinline__ void load8h(const __hip_bfloat16* p, float* f) {
  const __hip_bfloat162* p2 = (const __hip_bfloat162*)p;
  #pragma unroll
  for (int i = 0; i < 4; ++i) {
    float2 xy = __bfloat1622float2(p2[i]);
    f[2 * i] = xy.x; f[2 * i + 1] = xy.y;
  }
}

__global__ __launch_bounds__(512) void k4_main(const float* __restrict__ img,
                                               const float* __restrict__ scale_p,
                                               const float* __restrict__ ws,
                                               float* __restrict__ out) {
  __shared__ float s_sc[LV];
  __shared__ int   s_kidx[NKEEP];
  __shared__ int   s_nidx[NNON];
  __shared__ int   s_cnt[2];
  __shared__ float s_wk[NNON];
  __shared__ __align__(16) float s_w[KEEPED * NKEEP];        // 19.2 KB; also temp
  __shared__ __align__(16) __hip_bfloat16 s_selh[50 * CDIM]; // 50 KB
  __shared__ float s_red[128];

  int b = blockIdx.x;
  int v = b >> 5, t = b & 31;
  int tid = threadIdx.x;
  int wv = tid >> 6, lane = tid & 63;

  if (tid < 2) s_cnt[tid] = 0;
  if (tid < LV) s_sc[tid] = ws[WS_SCORE + ((size_t)t * BV + v) * LV + tid];
  __syncthreads();

  // --- rank & partition (stable argsort of -score semantics) ---
  if (tid < LV) {
    float my = s_sc[tid];
    int cnt = 0;
    for (int j = 0; j < LV; ++j) {
      float sj = s_sc[j];
      cnt += (sj > my) || (sj == my && j < tid);
    }
    bool keep = cnt < NKEEP;
    out[BV * BT + ((size_t)t * BV + v) * LV + tid] = keep ? 1.f : 0.f;
    if (keep) { int p = atomicAdd(&s_cnt[0], 1); s_kidx[p] = tid; }
    else      { int p = atomicAdd(&s_cnt[1], 1); s_nidx[p] = tid; }
  }
  __syncthreads();

  // --- softmax over non-kept scores ---
  if (tid < 128) s_red[tid] = (tid < NNON) ? s_sc[s_nidx[tid]] : -3.0e38f;
  __syncthreads();
  for (int off = 64; off > 0; off >>= 1) {
    if (tid < off) s_red[tid] = fmaxf(s_red[tid], s_red[tid + off]);
    __syncthreads();
  }
  float nm = s_red[0];
  __syncthreads();
  float e = 0.f;
  if (tid < NNON) e = expf(s_sc[s_nidx[tid]] - nm);
  if (tid < 128) s_red[tid] = (tid < NNON) ? e : 0.f;
  __syncthreads();
  for (int off = 64; off > 0; off >>= 1) {
    if (tid < off) s_red[tid] += s_red[tid + off];
    __syncthreads();
  }
  float nS = s_red[0];
  __syncthreads();
  if (tid < NNON) s_wk[tid] = e / nS;
  __syncthreads();

  // --- extra token (pool 49): 4 k-groups x 128 quads, partials in s_w ---
  {
    int kg = tid >> 7, q = tid & 127;
    float4 acc = make_float4(0.f, 0.f, 0.f, 0.f);
    for (int k = kg; k < NNON; k += 4) {
      const float4* row = (const float4*)(img + ((size_t)v * LV + s_nidx[k]) * CDIM);
      float w = s_wk[k];
      float4 tv = row[q];
      acc.x += w * tv.x; acc.y += w * tv.y; acc.z += w * tv.z; acc.w += w * tv.w;
    }
    ((float4*)s_w)[kg * 128 + q] = acc;
  }
  __syncthreads();
  float4 ex = make_float4(0.f, 0.f, 0.f, 0.f);
  if (tid < 128) {
    #pragma unroll
    for (int g = 0; g < 4; ++g) {
      float4 pv = ((float4*)s_w)[g * 128 + tid];
      ex.x += pv.x; ex.y += pv.y; ex.z += pv.z; ex.w += pv.w;
    }
    s_red[tid] = ex.x * ex.x + ex.y * ex.y + ex.z * ex.z + ex.w * ex.w;
  }
  __syncthreads();
  for (int off = 64; off > 0; off >>= 1) {
    if (tid < off) s_red[tid] += s_red[tid + off];
    __syncthreads();
  }
  float exinv = 1.f / fmaxf(sqrtf(s_red[0]), 1e-12f);
  __syncthreads();
  if (tid < 128) {
    s_selh[49 * CDIM + 4 * tid + 0] = __float2bfloat16(ex.x * exinv);
    s_selh[49 * CDIM + 4 * tid + 1] = __float2bfloat16(ex.y * exinv);
    s_selh[49 * CDIM + 4 * tid + 2] = __float2bfloat16(ex.z * exinv);
    s_selh[49 * CDIM + 4 * tid + 3] = __float2bfloat16(ex.w * exinv);
  }
  __syncthreads();   // s_w about to be overwritten by wlog

  // --- pool logits: gather wlog of kept tokens, * scale ---
  float scale_val = scale_p[0];
  for (int i = tid; i < KEEPED * NKEEP; i += 512) {
    int k = i / KEEPED, p = i - k * KEEPED;
    s_w[p * NKEEP + k] = ws[WS_WLOG + ((size_t)v * LV + s_kidx[k]) * KEEPED + p] * scale_val;
  }
  __syncthreads();

  // --- softmax over k per pool: 8-lane groups, 49*8 = 392 threads ---
  if (tid < KEEPED * 8) {
    int p = tid >> 3, g = tid & 7;
    float mm = -3e38f;
    for (int k = g; k < NKEEP; k += 8) mm = fmaxf(mm, s_w[p * NKEEP + k]);
    #pragma unroll
    for (int off = 4; off > 0; off >>= 1) mm = fmaxf(mm, __shfl_xor(mm, off, 8));
    float ss = 0.f;
    for (int k = g; k < NKEEP; k += 8) {
      float ee = expf(s_w[p * NKEEP + k] - mm);
      s_w[p * NKEEP + k] = ee;
      ss += ee;
    }
    #pragma unroll
    for (int off = 4; off > 0; off >>= 1) ss += __shfl_xor(ss, off, 8);
    float rs = 1.f / ss;
    for (int k = g; k < NKEEP; k += 8) s_w[p * NKEEP + k] *= rs;
  }
  __syncthreads();

  // --- aggr: barrier-free K-loop. wave wv owns pools {wv+8i, i<7}.
  //     Lane covers channels [4*lane,4*lane+4) and [256+4*lane, ...). ---
  float4 a0[7], a1[7];
  #pragma unroll
  for (int i = 0; i < 7; ++i) {
    a0[i] = make_float4(0.f, 0.f, 0.f, 0.f);
    a1[i] = make_float4(0.f, 0.f, 0.f, 0.f);
  }
  const float4* ibase = (const float4*)(img + (size_t)v * LV * CDIM);
  #pragma unroll 2
  for (int k = 0; k < NKEEP; ++k) {
    const float4* rp = ibase + (size_t)s_kidx[k] * 128;
    float4 tv0 = rp[lane];
    float4 tv1 = rp[lane + 64];
    #pragma unroll
    for (int i = 0; i < 7; ++i) {
      int p = wv + 8 * i;
      if (p < KEEPED) {
        float w = s_w[p * NKEEP + k];
        a0[i].x += w * tv0.x; a0[i].y += w * tv0.y;
        a0[i].z += w * tv0.z; a0[i].w += w * tv0.w;
        a1[i].x += w * tv1.x; a1[i].y += w * tv1.y;
        a1[i].z += w * tv1.z; a1[i].w += w * tv1.w;
      }
    }
  }
  // fused l2norm + bf16 store
  #pragma unroll
  for (int i = 0; i < 7; ++i) {
    int p = wv + 8 * i;
    if (p < KEEPED) {
      float ss = a0[i].x*a0[i].x + a0[i].y*a0[i].y + a0[i].z*a0[i].z + a0[i].w*a0[i].w
               + a1[i].x*a1[i].x + a1[i].y*a1[i].y + a1[i].z*a1[i].z + a1[i].w*a1[i].w;
      #pragma unroll
      for (int off = 32; off > 0; off >>= 1) ss += __shfl_xor(ss, off, 64);
      float inv = 1.f / fmaxf(sqrtf(ss), 1e-12f);
      __hip_bfloat16* d0 = s_selh + p * CDIM + 4 * lane;
      d0[0] = __float2bfloat16(a0[i].x * inv);
      d0[1] = __float2bfloat16(a0[i].y * inv);
      d0[2] = __float2bfloat16(a0[i].z * inv);
      d0[3] = __float2bfloat16(a0[i].w * inv);
      __hip_bfloat16* d1 = d0 + 256;
      d1[0] = __float2bfloat16(a1[i].x * inv);
      d1[1] = __float2bfloat16(a1[i].y * inv);
      d1[2] = __float2bfloat16(a1[i].z * inv);
      d1[3] = __float2bfloat16(a1[i].w * inv);
    }
  }
  __syncthreads();

  // --- per-word: sims -> softmax -> ctx -> l2norm -> word_sim; wave/word.
  //     Lane covers channels [8*lane, 8*lane+8). ---
  float wsum = 0.f;
  const float* capb = ws + WS_CAPNORM + (size_t)t * NW * CDIM;
  for (int w = wv; w < NW; w += 8) {
    const float4* cap4 = (const float4*)(capb + (size_t)w * CDIM);
    float4 cva = cap4[2 * lane], cvb = cap4[2 * lane + 1];
    float cv[8] = {cva.x, cva.y, cva.z, cva.w, cvb.x, cvb.y, cvb.z, cvb.w};
    float mylogit = -3e38f, simmax = -3e38f;
    for (int p = 0; p < 50; ++p) {
      float f[8];
      load8h(s_selh + p * CDIM + 8 * lane, f);
      float s = 0.f;
      #pragma unroll
      for (int j = 0; j < 8; ++j) s += cv[j] * f[j];
      #pragma unroll
      for (int off = 32; off > 0; off >>= 1) s += __shfl_xor(s, off, 64);
      float lg = LAMBDA_ * s;
      if (lane == p) mylogit = lg;
      simmax = fmaxf(simmax, lg);
    }
    float ee = (lane < 50) ? expf(mylogit - simmax) : 0.f;
    float d = ee;
    #pragma unroll
    for (int off = 32; off > 0; off >>= 1) d += __shfl_xor(d, off, 64);
    float attn = ee / d;
    float ctx[8];
    #pragma unroll
    for (int j = 0; j < 8; ++j) ctx[j] = 0.f;
    for (int p = 0; p < 50; ++p) {
      float a = __shfl(attn, p, 64);
      float f[8];
      load8h(s_selh + p * CDIM + 8 * lane, f);
      #pragma unroll
      for (int j = 0; j < 8; ++j) ctx[j] += a * f[j];
    }
    float ss = 0.f, cw = 0.f;
    #pragma unroll
    for (int j = 0; j < 8; ++j) { ss += ctx[j] * ctx[j]; cw += ctx[j] * cv[j]; }
    #pragma unroll
    for (int off = 32; off > 0; off >>= 1) { ss += __shfl_xor(ss, off, 64); cw += __shfl_xor(cw, off, 64); }
    wsum += cw / fmaxf(sqrtf(ss), 1e-12f);
  }
  if (lane == 0) s_red[wv] = wsum;
  __syncthreads();
  if (tid == 0) {
    float s = 0.f;
    #pragma unroll
    for (int i = 0; i < 8; ++i) s += s_red[i];
    out[(size_t)v * BT + t] = s / (float)NW;   // improve_sims = sim.T
  }
}

// ---------------------------------------------------------------------------
extern "C" void kernel_launch(void* const* d_in, const int* in_sizes, int n_in,
                              void* d_out, int out_size, void* d_ws, size_t ws_size,
                              hipStream_t stream) {
  const float* img   = (const float*)d_in[0];
  const float* cap   = (const float*)d_in[1];
  // d_in[2] = cap_lens (unused by forward)
  const float* gamma = (const float*)d_in[3];
  const float* beta  = (const float*)d_in[4];
  const float* W1    = (const float*)d_in[5];
  const float* b1    = (const float*)d_in[6];
  const float* W2    = (const float*)d_in[7];
  const float* b2    = (const float*)d_in[8];
  const float* scale = (const float*)d_in[9];
  float* ws  = (float*)d_ws;
  float* out = (float*)d_out;

  k1_glo <<<dim3(BT + BV), dim3(256), 0, stream>>>(img, cap, ws);
  k2_token<<<dim3(BV, (LV + TOK - 1) / TOK), dim3(256), 0, stream>>>(img, gamma, beta, W1, b1, W2, b2, ws);
  k3_score<<<dim3(BV, 4), dim3(256), 0, stream>>>(img, ws);
  k4_main <<<dim3(BV * BT), dim3(512), 0, stream>>>(img, scale, ws, out);
}

// Round 5
// 669.562 us; speedup vs baseline: 3.2569x; 1.2429x over previous
//
#include <hip/hip_runtime.h>
#include <hip/hip_bf16.h>
#include <math.h>

#define CDIM 512
#define LV 196
#define BV 64
#define BT 32
#define NW 24
#define NKEEP 98
#define NNON 98      // LV - NKEEP
#define KEEPED 49
#define HID 102
#define LAMBDA_ 4.0f
#define LN_EPS_ 1e-5f

// ws layout (float offsets)
#define WS_CAPNORM 0
#define WS_CAPGLO  (WS_CAPNORM + BT*NW*CDIM)     // 393216
#define WS_IMGGLO  (WS_CAPGLO + BT*CDIM)         // +16384
#define WS_INVN    (WS_IMGGLO + BV*CDIM)         // +32768
#define WS_WLOG    (WS_INVN + BV*LV)             // +12544
#define WS_SCORE   (WS_WLOG + BV*LV*KEEPED)      // +614656
// total = 1470976 floats = 5.88 MB

typedef short v8s __attribute__((ext_vector_type(8)));   // 8 bf16 (4 VGPR)
typedef float v4f __attribute__((ext_vector_type(4)));
#define MFMA16(a, b, c) __builtin_amdgcn_mfma_f32_16x16x32_bf16((a), (b), (c), 0, 0, 0)

// LDS strides (elements), padded for bank behavior + alignment:
#define WA_STR 232    // A matrix rows (464 B, 16-aligned, 2-way banks)
#define TOK_STR 40    // token K-tile rows (80 B, 16-aligned, 2-way banks)
#define SEL_STR 520   // sel rows (1040 B, 16-aligned, 2-way banks)
#define G_STR 66      // Gram rows (f32)

// ---------------------------------------------------------------------------
// K1: cap_norm, cap_glo (blocks 0..31), img_glo (blocks 32..95). 256 thr.
// ---------------------------------------------------------------------------
__global__ __launch_bounds__(256) void k1_glo(const float* __restrict__ img,
                                              const float* __restrict__ cap,
                                              float* __restrict__ ws) {
  __shared__ float red[256];
  int b = blockIdx.x, tid = threadIdx.x;
  int c0 = tid, c1 = tid + 256;
  if (b < BT) {
    int t = b;
    float s0 = 0.f, s1 = 0.f;
    for (int w = 0; w < NW; ++w) {
      const float* p = cap + ((size_t)t * NW + w) * CDIM;
      float x0 = p[c0], x1 = p[c1];
      red[tid] = x0 * x0 + x1 * x1;
      __syncthreads();
      for (int off = 128; off > 0; off >>= 1) {
        if (tid < off) red[tid] += red[tid + off];
        __syncthreads();
      }
      float inv = 1.f / fmaxf(sqrtf(red[0]), 1e-12f);
      __syncthreads();
      float* q = ws + WS_CAPNORM + ((size_t)t * NW + w) * CDIM;
      q[c0] = x0 * inv; q[c1] = x1 * inv;
      s0 += x0; s1 += x1;
    }
    float g0 = s0 / (float)NW, g1 = s1 / (float)NW;
    red[tid] = g0 * g0 + g1 * g1;
    __syncthreads();
    for (int off = 128; off > 0; off >>= 1) {
      if (tid < off) red[tid] += red[tid + off];
      __syncthreads();
    }
    float inv = 1.f / fmaxf(sqrtf(red[0]), 1e-12f);
    float* q = ws + WS_CAPGLO + (size_t)t * CDIM;
    q[c0] = g0 * inv; q[c1] = g1 * inv;
  } else {
    int v = b - BT;
    float s0 = 0.f, s1 = 0.f;
    const float* base = img + (size_t)v * LV * CDIM;
    for (int l = 0; l < LV; ++l) { s0 += base[l * CDIM + c0]; s1 += base[l * CDIM + c1]; }
    float g0 = s0 / (float)LV, g1 = s1 / (float)LV;
    red[tid] = g0 * g0 + g1 * g1;
    __syncthreads();
    for (int off = 128; off > 0; off >>= 1) {
      if (tid < off) red[tid] += red[tid + off];
      __syncthreads();
    }
    float inv = 1.f / fmaxf(sqrtf(red[0]), 1e-12f);
    float* q = ws + WS_IMGGLO + (size_t)v * CDIM;
    q[c0] = g0 * inv; q[c1] = g1 * inv;
  }
}

// ---------------------------------------------------------------------------
// K2: per img token: inv_norm, LN, MLP(gelu) -> wlog. (unchanged this round)
// ---------------------------------------------------------------------------
#define TOK 8
__global__ __launch_bounds__(256) void k2_token(
    const float* __restrict__ img, const float* __restrict__ gamma,
    const float* __restrict__ beta, const float* __restrict__ W1,
    const float* __restrict__ b1, const float* __restrict__ W2,
    const float* __restrict__ b2, float* __restrict__ ws) {
  __shared__ float raw[TOK * CDIM];
  __shared__ float xn[TOK * CDIM];
  __shared__ float w1t[64 * HID];
  __shared__ float hbuf[TOK * HID];
  __shared__ float st_mean[TOK], st_rstd[TOK], st_invn[TOK];

  int v = blockIdx.x;
  int l0 = blockIdx.y * TOK;
  int tid = threadIdx.x;
  int nval = LV - l0; if (nval > TOK) nval = TOK; if (nval < 0) nval = 0;
  int wv = tid >> 6, lane = tid & 63;

  for (int i = tid; i < TOK * CDIM; i += 256) {
    int tok = i >> 9;
    raw[i] = (tok < nval) ? img[((size_t)v * LV + l0 + tok) * CDIM + (i & (CDIM - 1))] : 0.f;
  }
  __syncthreads();
  for (int tok = wv * 2; tok < wv * 2 + 2; ++tok) {
    float s = 0.f, sq = 0.f;
    #pragma unroll
    for (int j = 0; j < 8; ++j) { float x = raw[tok * CDIM + lane + 64 * j]; s += x; sq += x * x; }
    #pragma unroll
    for (int off = 32; off > 0; off >>= 1) { s += __shfl_xor(s, off, 64); sq += __shfl_xor(sq, off, 64); }
    if (lane == 0) {
      float mean = s / (float)CDIM;
      float var = sq / (float)CDIM - mean * mean;
      st_mean[tok] = mean;
      st_rstd[tok] = 1.f / sqrtf(var + LN_EPS_);
      st_invn[tok] = 1.f / fmaxf(sqrtf(sq), 1e-12f);
    }
  }
  __syncthreads();
  if (tid < nval) ws[WS_INVN + (size_t)v * LV + l0 + tid] = st_invn[tid];
  for (int i = tid; i < TOK * CDIM; i += 256) {
    int tok = i >> 9, c = i & (CDIM - 1);
    xn[i] = (raw[i] - st_mean[tok]) * st_rstd[tok] * gamma[c] + beta[c];
  }
  __syncthreads();

  float acc1[4];
  int hh[4], tt[4]; bool av[4];
  #pragma unroll
  for (int s = 0; s < 4; ++s) {
    int oi = tid + 256 * s;
    av[s] = oi < TOK * HID;
    hh[s] = av[s] ? (oi % HID) : 0;
    tt[s] = av[s] ? (oi / HID) : 0;
    acc1[s] = av[s] ? b1[hh[s]] : 0.f;
  }
  for (int ct = 0; ct < 8; ++ct) {
    for (int i = tid; i < 64 * HID; i += 256) w1t[i] = W1[ct * 64 * HID + i];
    __syncthreads();
    for (int cc = 0; cc < 64; ++cc) {
      #pragma unroll
      for (int s = 0; s < 4; ++s)
        acc1[s] += xn[tt[s] * CDIM + ct * 64 + cc] * w1t[cc * HID + hh[s]];
    }
    __syncthreads();
  }
  #pragma unroll
  for (int s = 0; s < 4; ++s) {
    if (av[s]) {
      float x = acc1[s];
      float g = 0.5f * x * (1.f + erff(x * 0.70710678118654752f));
      hbuf[tid + 256 * s] = g;
    }
  }
  __syncthreads();

  #pragma unroll
  for (int s = 0; s < 2; ++s) {
    int oi = tid + 256 * s;
    if (oi < TOK * KEEPED) {
      int p = oi % KEEPED, tok = oi / KEEPED;
      float a = b2[p];
      for (int h2 = 0; h2 < HID; ++h2) a += hbuf[tok * HID + h2] * W2[h2 * KEEPED + p];
      if (tok < nval)
        ws[WS_WLOG + ((size_t)v * LV + l0 + tok) * KEEPED + p] = a;
    }
  }
}

// ---------------------------------------------------------------------------
// K3: scores. (unchanged this round)
// ---------------------------------------------------------------------------
__global__ __launch_bounds__(256) void k3_score(const float* __restrict__ img,
                                                float* __restrict__ ws) {
  __shared__ float qt[33 * 64];
  __shared__ float xt[64 * 65];
  __shared__ float dself[64];
  int v = blockIdx.x;
  int t0 = blockIdx.y * 64;
  int tid = threadIdx.x;
  int tloc = tid & 63, qg = tid >> 6;
  float acc[9];
  #pragma unroll
  for (int i = 0; i < 9; ++i) acc[i] = 0.f;
  const float* capglo = ws + WS_CAPGLO;
  const float* imgglo = ws + WS_IMGGLO + (size_t)v * CDIM;

  for (int ct = 0; ct < 8; ++ct) {
    for (int i = tid; i < 33 * 64; i += 256) {
      int q = i >> 6, cc = i & 63;
      qt[i] = (q < 32) ? capglo[(size_t)q * CDIM + ct * 64 + cc] : imgglo[ct * 64 + cc];
    }
    for (int i = tid; i < 64 * 64; i += 256) {
      int tok = i >> 6, cc = i & 63;
      int l = t0 + tok;
      xt[tok * 65 + cc] = (l < LV) ? img[((size_t)v * LV + l) * CDIM + ct * 64 + cc] : 0.f;
    }
    __syncthreads();
    for (int cc = 0; cc < 64; ++cc) {
      float xv = xt[tloc * 65 + cc];
      #pragma unroll
      for (int qi = 0; qi < 9; ++qi) {
        int q = qg + 4 * qi;
        if (q < 33) acc[qi] += qt[q * 64 + cc] * xv;
      }
    }
    __syncthreads();
  }
  if (qg == 0) dself[tloc] = acc[8];
  __syncthreads();
  int l = t0 + tloc;
  if (l < LV) {
    float invn = ws[WS_INVN + (size_t)v * LV + l];
    float ds = dself[tloc];
    #pragma unroll
    for (int qi = 0; qi < 9; ++qi) {
      int q = qg + 4 * qi;
      if (q < 32) ws[WS_SCORE + ((size_t)q * BV + v) * LV + l] = (acc[qi] + ds) * invn;
    }
  }
}

// ---------------------------------------------------------------------------
// K4 (R5): MFMA everywhere matmul-shaped.
//  - aggr+extra as ONE GEMM: A[64 pools x 224 tok-basis] @ B[tok x 512 ch],
//    A row p<49 = softmaxed w scattered to kept-token slots (zeros else),
//    row 49 = non-kept softmax weights, rows 50..63 = 0. B staged per
//    K-step (32 tokens) channel-major bf16 in LDS.
//  - word phase via Gram trick: s = cap.sel^T (MFMA), e = exp(4s - max),
//    num = sum e*s; G = sel.sel^T (MFMA, both operands same LDS array);
//    word_sim = num / sqrt(e^T G e).  (Z cancels.)
// 512 thr (8 waves), LDS ~137 KB -> 1 block/CU; __launch_bounds__(512,2)
// gives the 256-VGPR budget (R1/R2 lesson: default cap causes spills).
// ---------------------------------------------------------------------------
__global__ __launch_bounds__(512, 2) void k4_main(const float* __restrict__ img,
                                                  const float* __restrict__ scale_p,
                                                  const float* __restrict__ ws,
                                                  float* __restrict__ out) {
  __shared__ float s_sc[LV];
  __shared__ int   s_kidx[NKEEP];
  __shared__ int   s_nidx[NNON];
  __shared__ int   s_cnt[2];
  __shared__ float s_wk[NNON];
  __shared__ float s_red[128];
  __shared__ float s_pool2[64];
  __shared__ float s_inv[64];
  __shared__ __align__(16) __hip_bfloat16 s_selh[64 * SEL_STR];  // 66.6 KB (rows 50..63 zero)
  __shared__ __align__(16) __hip_bfloat16 s_wa[64 * WA_STR];     // 29.7 KB; later: s_sims + s_G
  __shared__ __align__(16) __hip_bfloat16 s_dyn[512 * TOK_STR];  // 41 KB; s_w / tok-tile / cap_b

  float* s_w = (float*)s_dyn;                       // 49*98 f32 = 19.2 KB
  __hip_bfloat16* s_tok = s_dyn;                    // [512 c][TOK_STR]
  __hip_bfloat16* s_cap = s_dyn;                    // [32 w][SEL_STR] = 33.3 KB
  float* s_sims = (float*)s_wa;                     // [32 w][64 p] f32 = 8 KB
  float* s_G = (float*)((char*)s_wa + 8192);        // [64][G_STR] f32 = 16.9 KB

  int b = blockIdx.x;
  int v = b >> 5, t = b & 31;
  int tid = threadIdx.x;
  int wv = tid >> 6, lane = tid & 63;
  int quad = lane >> 4, l15 = lane & 15;
  int koff = quad * 8;

  // ---- P0: loads + zero-init ----
  if (tid < 2) s_cnt[tid] = 0;
  if (tid < 64) s_pool2[tid] = 0.f;
  if (tid < LV) s_sc[tid] = ws[WS_SCORE + ((size_t)t * BV + v) * LV + tid];
  {
    uint* za = (uint*)s_wa;                         // zero A matrix
    for (int i = tid; i < 64 * WA_STR / 2; i += 512) za[i] = 0u;
    uint* zs = (uint*)(s_selh + 50 * SEL_STR);      // zero sel rows 50..63
    for (int i = tid; i < 14 * SEL_STR / 2; i += 512) zs[i] = 0u;
  }
  __syncthreads();

  // ---- P1: rank & partition (stable argsort of -score semantics) ----
  if (tid < LV) {
    float my = s_sc[tid];
    int cnt = 0;
    for (int j = 0; j < LV; ++j) {
      float sj = s_sc[j];
      cnt += (sj > my) || (sj == my && j < tid);
    }
    bool keep = cnt < NKEEP;
    out[BV * BT + ((size_t)t * BV + v) * LV + tid] = keep ? 1.f : 0.f;
    if (keep) { int p = atomicAdd(&s_cnt[0], 1); s_kidx[p] = tid; }
    else      { int p = atomicAdd(&s_cnt[1], 1); s_nidx[p] = tid; }
  }
  __syncthreads();

  // ---- P2: softmax over non-kept scores -> s_wk ----
  if (tid < 128) s_red[tid] = (tid < NNON) ? s_sc[s_nidx[tid]] : -3.0e38f;
  __syncthreads();
  for (int off = 64; off > 0; off >>= 1) {
    if (tid < off) s_red[tid] = fmaxf(s_red[tid], s_red[tid + off]);
    __syncthreads();
  }
  float nm = s_red[0];
  __syncthreads();
  float e0 = 0.f;
  if (tid < NNON) e0 = expf(s_sc[s_nidx[tid]] - nm);
  if (tid < 128) s_red[tid] = (tid < NNON) ? e0 : 0.f;
  __syncthreads();
  for (int off = 64; off > 0; off >>= 1) {
    if (tid < off) s_red[tid] += s_red[tid + off];
    __syncthreads();
  }
  float nS = s_red[0];
  __syncthreads();
  if (tid < NNON) s_wk[tid] = e0 / nS;
  __syncthreads();

  // ---- P3: wlog gather -> s_w[p][r] fp32, softmax over r per pool ----
  float scale_val = scale_p[0];
  for (int i = tid; i < KEEPED * NKEEP; i += 512) {
    int k = i / KEEPED, p = i - k * KEEPED;
    s_w[p * NKEEP + k] = ws[WS_WLOG + ((size_t)v * LV + s_kidx[k]) * KEEPED + p] * scale_val;
  }
  __syncthreads();
  if (tid < KEEPED * 8) {
    int p = tid >> 3, g = tid & 7;
    float mm = -3e38f;
    for (int k = g; k < NKEEP; k += 8) mm = fmaxf(mm, s_w[p * NKEEP + k]);
    #pragma unroll
    for (int off = 4; off > 0; off >>= 1) mm = fmaxf(mm, __shfl_xor(mm, off, 8));
    float ss = 0.f;
    for (int k = g; k < NKEEP; k += 8) {
      float ee = expf(s_w[p * NKEEP + k] - mm);
      s_w[p * NKEEP + k] = ee;
      ss += ee;
    }
    #pragma unroll
    for (int off = 4; off > 0; off >>= 1) ss += __shfl_xor(ss, off, 8);
    float rs = 1.f / ss;
    for (int k = g; k < NKEEP; k += 8) s_w[p * NKEEP + k] *= rs;
  }
  __syncthreads();

  // ---- P4: scatter A = s_wa (bf16): kept weights + wk row 49 ----
  for (int i = tid; i < KEEPED * NKEEP; i += 512) {
    int p = i / NKEEP, r = i - p * NKEEP;
    s_wa[p * WA_STR + s_kidx[r]] = __float2bfloat16(s_w[p * NKEEP + r]);
  }
  if (tid < NNON) s_wa[49 * WA_STR + s_nidx[tid]] = __float2bfloat16(s_wk[tid]);
  __syncthreads();   // s_dyn repurposed as token tile next

  // ---- P5: aggr GEMM, K-loop of 7 x 32 tokens ----
  v4f acc[4][4];   // [mtile][ntile-local]; wave owns channels [wv*64, wv*64+64)
  #pragma unroll
  for (int m = 0; m < 4; ++m)
    #pragma unroll
    for (int j = 0; j < 4; ++j) acc[m][j] = (v4f){0.f, 0.f, 0.f, 0.f};

  for (int ks = 0; ks < 7; ++ks) {
    // stage 32 tokens channel-major bf16: s_tok[c][kl] = img[v][ks*32+kl][c]
    #pragma unroll
    for (int it = 0; it < 8; ++it) {
      int k0 = ks * 32 + it * 4;
      if (k0 < LV) {   // LV divisible by 4 -> all 4 valid
        const float* gp = img + ((size_t)v * LV + k0) * CDIM + tid;
        float x0 = gp[0], x1 = gp[CDIM], x2 = gp[2 * CDIM], x3 = gp[3 * CDIM];
        union { __hip_bfloat16 h[4]; uint2 u; } pk;
        pk.h[0] = __float2bfloat16(x0); pk.h[1] = __float2bfloat16(x1);
        pk.h[2] = __float2bfloat16(x2); pk.h[3] = __float2bfloat16(x3);
        *(uint2*)(s_tok + tid * TOK_STR + it * 4) = pk.u;
      }
    }
    __syncthreads();
    v8s bfr[4];
    #pragma unroll
    for (int j = 0; j < 4; ++j)
      bfr[j] = *(const v8s*)(s_tok + (wv * 64 + j * 16 + l15) * TOK_STR + koff);
    #pragma unroll
    for (int m = 0; m < 4; ++m) {
      v8s af = *(const v8s*)(s_wa + (m * 16 + l15) * WA_STR + ks * 32 + koff);
      #pragma unroll
      for (int j = 0; j < 4; ++j) acc[m][j] = MFMA16(af, bfr[j], acc[m][j]);
    }
    __syncthreads();
  }

  // ---- P6: cap staging (s_dyn free now) + pool l2norm ----
  for (int i = tid; i < NW * 128; i += 512) {     // 24 w x 128 quads
    int w = i >> 7, cq = i & 127;
    const float4 xv = *(const float4*)(ws + WS_CAPNORM + ((size_t)t * NW + w) * CDIM + cq * 4);
    union { __hip_bfloat16 h[4]; uint2 u; } pk;
    pk.h[0] = __float2bfloat16(xv.x); pk.h[1] = __float2bfloat16(xv.y);
    pk.h[2] = __float2bfloat16(xv.z); pk.h[3] = __float2bfloat16(xv.w);
    *(uint2*)(s_cap + w * SEL_STR + cq * 4) = pk.u;
  }
  {
    uint* zc = (uint*)(s_cap + 24 * SEL_STR);     // zero cap rows 24..31
    for (int i = tid; i < 8 * SEL_STR / 2; i += 512) zc[i] = 0u;
  }
  #pragma unroll
  for (int m = 0; m < 4; ++m) {
    #pragma unroll
    for (int reg = 0; reg < 4; ++reg) {
      float ss = acc[m][0][reg] * acc[m][0][reg] + acc[m][1][reg] * acc[m][1][reg]
               + acc[m][2][reg] * acc[m][2][reg] + acc[m][3][reg] * acc[m][3][reg];
      #pragma unroll
      for (int off = 8; off > 0; off >>= 1) ss += __shfl_xor(ss, off, 64);  // over l15
      if (l15 == 0) atomicAdd(&s_pool2[m * 16 + quad * 4 + reg], ss);
    }
  }
  __syncthreads();
  if (tid < 64) s_inv[tid] = 1.f / fmaxf(sqrtf(s_pool2[tid]), 1e-12f);
  __syncthreads();
  #pragma unroll
  for (int m = 0; m < 4; ++m) {
    #pragma unroll
    for (int reg = 0; reg < 4; ++reg) {
      int p = m * 16 + quad * 4 + reg;
      if (p < 50) {
        float iv = s_inv[p];
        #pragma unroll
        for (int j = 0; j < 4; ++j)
          s_selh[p * SEL_STR + wv * 64 + j * 16 + l15] = __float2bfloat16(acc[m][j][reg] * iv);
      }
    }
  }
  __syncthreads();

  // ---- P7: sims = cap . sel^T via MFMA; one 16x16 tile per wave ----
  {
    int mt = wv >> 2, nt = wv & 3;
    v4f sa = (v4f){0.f, 0.f, 0.f, 0.f};
    for (int ks = 0; ks < 16; ++ks) {
      v8s a = *(const v8s*)(s_cap + (mt * 16 + l15) * SEL_STR + ks * 32 + koff);
      v8s bb = *(const v8s*)(s_selh + (nt * 16 + l15) * SEL_STR + ks * 32 + koff);
      sa = MFMA16(a, bb, sa);
    }
    #pragma unroll
    for (int reg = 0; reg < 4; ++reg)
      s_sims[(mt * 16 + quad * 4 + reg) * 64 + nt * 16 + l15] = sa[reg];
  }
  __syncthreads();

  // ---- P8: per-word softmax (unnormalized e) + num = sum e*s ----
  if (tid < NW * 8) {
    int w = tid >> 3, g = tid & 7;
    float* row = s_sims + w * 64;
    float mm = -3e38f;
    for (int p = g; p < 50; p += 8) mm = fmaxf(mm, row[p]);
    #pragma unroll
    for (int off = 4; off > 0; off >>= 1) mm = fmaxf(mm, __shfl_xor(mm, off, 8));
    float num = 0.f;
    for (int p = g; p < 64; p += 8) {
      if (p < 50) {
        float s = row[p];
        float ee = expf(LAMBDA_ * (s - mm));
        num += ee * s;
        row[p] = ee;
      } else row[p] = 0.f;
    }
    #pragma unroll
    for (int off = 4; off > 0; off >>= 1) num += __shfl_xor(num, off, 8);
    if (g == 0) s_red[w] = num;
  }
  __syncthreads();

  // ---- P9: G = sel . sel^T via MFMA; 2 tiles per wave ----
  #pragma unroll
  for (int i2 = 0; i2 < 2; ++i2) {
    int idx = wv * 2 + i2;
    int gm = idx >> 2, gn = idx & 3;
    v4f ga = (v4f){0.f, 0.f, 0.f, 0.f};
    for (int ks = 0; ks < 16; ++ks) {
      v8s a = *(const v8s*)(s_selh + (gm * 16 + l15) * SEL_STR + ks * 32 + koff);
      v8s bb = *(const v8s*)(s_selh + (gn * 16 + l15) * SEL_STR + ks * 32 + koff);
      ga = MFMA16(a, bb, ga);
    }
    #pragma unroll
    for (int reg = 0; reg < 4; ++reg)
      s_G[(gm * 16 + quad * 4 + reg) * G_STR + gn * 16 + l15] = ga[reg];
  }
  __syncthreads();

  // ---- P10: word_sim = num / sqrt(e^T G e); mean over words ----
  float wacc = 0.f;
  for (int w = wv; w < NW; w += 8) {
    const float* ev = s_sims + w * 64;
    float tl = 0.f;
    for (int q = 0; q < 50; ++q) tl += s_G[q * G_STR + lane] * ev[q];
    float ql = ev[lane] * tl;
    #pragma unroll
    for (int off = 32; off > 0; off >>= 1) ql += __shfl_xor(ql, off, 64);
    if (lane == 0) wacc += s_red[w] / fmaxf(sqrtf(ql), 1e-20f);
  }
  if (lane == 0) s_red[64 + wv] = wacc;
  __syncthreads();
  if (tid == 0) {
    float s = 0.f;
    #pragma unroll
    for (int i = 0; i < 8; ++i) s += s_red[64 + i];
    out[(size_t)v * BT + t] = s / (float)NW;   // improve_sims = sim.T
  }
}

// ---------------------------------------------------------------------------
extern "C" void kernel_launch(void* const* d_in, const int* in_sizes, int n_in,
                              void* d_out, int out_size, void* d_ws, size_t ws_size,
                              hipStream_t stream) {
  const float* img   = (const float*)d_in[0];
  const float* cap   = (const float*)d_in[1];
  // d_in[2] = cap_lens (unused by forward)
  const float* gamma = (const float*)d_in[3];
  const float* beta  = (const float*)d_in[4];
  const float* W1    = (const float*)d_in[5];
  const float* b1    = (const float*)d_in[6];
  const float* W2    = (const float*)d_in[7];
  const float* b2    = (const float*)d_in[8];
  const float* scale = (const float*)d_in[9];
  float* ws  = (float*)d_ws;
  float* out = (float*)d_out;

  k1_glo <<<dim3(BT + BV), dim3(256), 0, stream>>>(img, cap, ws);
  k2_token<<<dim3(BV, (LV + TOK - 1) / TOK), dim3(256), 0, stream>>>(img, gamma, beta, W1, b1, W2, b2, ws);
  k3_score<<<dim3(BV, 4), dim3(256), 0, stream>>>(img, ws);
  k4_main <<<dim3(BV * BT), dim3(512), 0, stream>>>(img, scale, ws, out);
}

// Round 8
// 656.020 us; speedup vs baseline: 3.3241x; 1.0206x over previous
//
#include <hip/hip_runtime.h>
#include <hip/hip_bf16.h>
#include <math.h>

#define CDIM 512
#define LV 196
#define BV 64
#define BT 32
#define NW 24
#define NKEEP 98
#define NNON 98      // LV - NKEEP
#define KEEPED 49
#define HID 102
#define LAMBDA_ 4.0f
#define LN_EPS_ 1e-5f

// ws layout (float offsets)
#define WS_CAPNORM 0
#define WS_CAPGLO  (WS_CAPNORM + BT*NW*CDIM)     // 393216
#define WS_IMGGLO  (WS_CAPGLO + BT*CDIM)         // +16384
#define WS_IMGSUM  WS_IMGGLO                     // (alias, unused)
#define WS_INVN    (WS_IMGGLO + BV*CDIM)         // +32768
#define WS_WLOG    (WS_INVN + BV*LV)             // +12544
#define WS_SCORE   (WS_WLOG + BV*LV*KEEPED)      // +614656
#define WS_END     (WS_SCORE + BT*BV*LV)         // 1470976 floats = 5.88 MB
// imgT (big path only): bf16 [64][512][224] appended after WS_END
#define WS_IMGT_B  ((size_t)WS_END * 4)          // byte offset 5883904
#define TOKPAD 224
#define WS_NEED_B  (WS_IMGT_B + (size_t)BV * CDIM * TOKPAD * 2)   // 20563968 B

typedef short v8s __attribute__((ext_vector_type(8)));   // 8 bf16 (4 VGPR)
typedef float v4f __attribute__((ext_vector_type(4)));
#define MFMA16(a, b, c) __builtin_amdgcn_mfma_f32_16x16x32_bf16((a), (b), (c), 0, 0, 0)

// LDS strides (elements), padded for bank behavior + alignment:
#define WA_STR 232    // A matrix rows (464 B, 16-aligned, 2-way banks)
#define TOK_STR 40    // token K-tile rows (80 B, 16-aligned)
#define SEL_STR 520   // sel rows (1040 B, 16-aligned, 2-way banks)
#define G_STR 66      // Gram rows (f32)

__device__ __forceinline__ ushort bfb(float f) {
  __hip_bfloat16 h = __float2bfloat16(f);
  union { __hip_bfloat16 h; ushort u; } cv; cv.h = h; return cv.u;
}

// ---------------------------------------------------------------------------
// K0 (big path only): imgT[v][c][tok] bf16, tok padded 196->224 with zeros.
// grid (64 v, 7 ktile), 512 thr (one channel each). Pure transpose+convert.
// ---------------------------------------------------------------------------
__global__ __launch_bounds__(512) void k0_prep(const float* __restrict__ img,
                                               float* __restrict__ ws) {
  int v = blockIdx.x, kt = blockIdx.y, c = threadIdx.x;
  float x[32];
  #pragma unroll
  for (int kk = 0; kk < 32; ++kk) {
    int tok = kt * 32 + kk;
    x[kk] = (tok < LV) ? img[((size_t)v * LV + tok) * CDIM + c] : 0.f;
  }
  __hip_bfloat16* imgT = (__hip_bfloat16*)((char*)ws + WS_IMGT_B);
  uint* dst = (uint*)(imgT + ((size_t)v * CDIM + c) * TOKPAD + kt * 32);
  #pragma unroll
  for (int g = 0; g < 4; ++g) {
    uint4 u;
    u.x = (uint)bfb(x[g*8+0]) | ((uint)bfb(x[g*8+1]) << 16);
    u.y = (uint)bfb(x[g*8+2]) | ((uint)bfb(x[g*8+3]) << 16);
    u.z = (uint)bfb(x[g*8+4]) | ((uint)bfb(x[g*8+5]) << 16);
    u.w = (uint)bfb(x[g*8+6]) | ((uint)bfb(x[g*8+7]) << 16);
    *(uint4*)(dst + g * 4) = u;
  }
}

// ---------------------------------------------------------------------------
// K1: cap_norm, cap_glo (blocks 0..31), img_glo (blocks 32..95). 256 thr.
// (verbatim R5-passing version)
// ---------------------------------------------------------------------------
__global__ __launch_bounds__(256) void k1_glo(const float* __restrict__ img,
                                              const float* __restrict__ cap,
                                              float* __restrict__ ws) {
  __shared__ float red[256];
  int b = blockIdx.x, tid = threadIdx.x;
  int c0 = tid, c1 = tid + 256;
  if (b < BT) {
    int t = b;
    float s0 = 0.f, s1 = 0.f;
    for (int w = 0; w < NW; ++w) {
      const float* p = cap + ((size_t)t * NW + w) * CDIM;
      float x0 = p[c0], x1 = p[c1];
      red[tid] = x0 * x0 + x1 * x1;
      __syncthreads();
      for (int off = 128; off > 0; off >>= 1) {
        if (tid < off) red[tid] += red[tid + off];
        __syncthreads();
      }
      float inv = 1.f / fmaxf(sqrtf(red[0]), 1e-12f);
      __syncthreads();
      float* q = ws + WS_CAPNORM + ((size_t)t * NW + w) * CDIM;
      q[c0] = x0 * inv; q[c1] = x1 * inv;
      s0 += x0; s1 += x1;
    }
    float g0 = s0 / (float)NW, g1 = s1 / (float)NW;
    red[tid] = g0 * g0 + g1 * g1;
    __syncthreads();
    for (int off = 128; off > 0; off >>= 1) {
      if (tid < off) red[tid] += red[tid + off];
      __syncthreads();
    }
    float inv = 1.f / fmaxf(sqrtf(red[0]), 1e-12f);
    float* q = ws + WS_CAPGLO + (size_t)t * CDIM;
    q[c0] = g0 * inv; q[c1] = g1 * inv;
  } else {
    int v = b - BT;
    float s0 = 0.f, s1 = 0.f;
    const float* base = img + (size_t)v * LV * CDIM;
    for (int l = 0; l < LV; ++l) { s0 += base[l * CDIM + c0]; s1 += base[l * CDIM + c1]; }
    float g0 = s0 / (float)LV, g1 = s1 / (float)LV;
    red[tid] = g0 * g0 + g1 * g1;
    __syncthreads();
    for (int off = 128; off > 0; off >>= 1) {
      if (tid < off) red[tid] += red[tid + off];
      __syncthreads();
    }
    float inv = 1.f / fmaxf(sqrtf(red[0]), 1e-12f);
    float* q = ws + WS_IMGGLO + (size_t)v * CDIM;
    q[c0] = g0 * inv; q[c1] = g1 * inv;
  }
}

// ---------------------------------------------------------------------------
// K2: per img token: inv_norm, LN, MLP(gelu) -> wlog. (verbatim R5)
// ---------------------------------------------------------------------------
#define TOK 8
__global__ __launch_bounds__(256) void k2_token(
    const float* __restrict__ img, const float* __restrict__ gamma,
    const float* __restrict__ beta, const float* __restrict__ W1,
    const float* __restrict__ b1, const float* __restrict__ W2,
    const float* __restrict__ b2, float* __restrict__ ws) {
  __shared__ float raw[TOK * CDIM];
  __shared__ float xn[TOK * CDIM];
  __shared__ float w1t[64 * HID];
  __shared__ float hbuf[TOK * HID];
  __shared__ float st_mean[TOK], st_rstd[TOK], st_invn[TOK];

  int v = blockIdx.x;
  int l0 = blockIdx.y * TOK;
  int tid = threadIdx.x;
  int nval = LV - l0; if (nval > TOK) nval = TOK; if (nval < 0) nval = 0;
  int wv = tid >> 6, lane = tid & 63;

  for (int i = tid; i < TOK * CDIM; i += 256) {
    int tok = i >> 9;
    raw[i] = (tok < nval) ? img[((size_t)v * LV + l0 + tok) * CDIM + (i & (CDIM - 1))] : 0.f;
  }
  __syncthreads();
  for (int tok = wv * 2; tok < wv * 2 + 2; ++tok) {
    float s = 0.f, sq = 0.f;
    #pragma unroll
    for (int j = 0; j < 8; ++j) { float x = raw[tok * CDIM + lane + 64 * j]; s += x; sq += x * x; }
    #pragma unroll
    for (int off = 32; off > 0; off >>= 1) { s += __shfl_xor(s, off, 64); sq += __shfl_xor(sq, off, 64); }
    if (lane == 0) {
      float mean = s / (float)CDIM;
      float var = sq / (float)CDIM - mean * mean;
      st_mean[tok] = mean;
      st_rstd[tok] = 1.f / sqrtf(var + LN_EPS_);
      st_invn[tok] = 1.f / fmaxf(sqrtf(sq), 1e-12f);
    }
  }
  __syncthreads();
  if (tid < nval) ws[WS_INVN + (size_t)v * LV + l0 + tid] = st_invn[tid];
  for (int i = tid; i < TOK * CDIM; i += 256) {
    int tok = i >> 9, c = i & (CDIM - 1);
    xn[i] = (raw[i] - st_mean[tok]) * st_rstd[tok] * gamma[c] + beta[c];
  }
  __syncthreads();

  float acc1[4];
  int hh[4], tt[4]; bool av[4];
  #pragma unroll
  for (int s = 0; s < 4; ++s) {
    int oi = tid + 256 * s;
    av[s] = oi < TOK * HID;
    hh[s] = av[s] ? (oi % HID) : 0;
    tt[s] = av[s] ? (oi / HID) : 0;
    acc1[s] = av[s] ? b1[hh[s]] : 0.f;
  }
  for (int ct = 0; ct < 8; ++ct) {
    for (int i = tid; i < 64 * HID; i += 256) w1t[i] = W1[ct * 64 * HID + i];
    __syncthreads();
    for (int cc = 0; cc < 64; ++cc) {
      #pragma unroll
      for (int s = 0; s < 4; ++s)
        acc1[s] += xn[tt[s] * CDIM + ct * 64 + cc] * w1t[cc * HID + hh[s]];
    }
    __syncthreads();
  }
  #pragma unroll
  for (int s = 0; s < 4; ++s) {
    if (av[s]) {
      float x = acc1[s];
      float g = 0.5f * x * (1.f + erff(x * 0.70710678118654752f));
      hbuf[tid + 256 * s] = g;
    }
  }
  __syncthreads();

  #pragma unroll
  for (int s = 0; s < 2; ++s) {
    int oi = tid + 256 * s;
    if (oi < TOK * KEEPED) {
      int p = oi % KEEPED, tok = oi / KEEPED;
      float a = b2[p];
      for (int h2 = 0; h2 < HID; ++h2) a += hbuf[tok * HID + h2] * W2[h2 * KEEPED + p];
      if (tok < nval)
        ws[WS_WLOG + ((size_t)v * LV + l0 + tok) * KEEPED + p] = a;
    }
  }
}

// ---------------------------------------------------------------------------
// K3: scores. (verbatim R5)
// ---------------------------------------------------------------------------
__global__ __launch_bounds__(256) void k3_score(const float* __restrict__ img,
                                                float* __restrict__ ws) {
  __shared__ float qt[33 * 64];
  __shared__ float xt[64 * 65];
  __shared__ float dself[64];
  int v = blockIdx.x;
  int t0 = blockIdx.y * 64;
  int tid = threadIdx.x;
  int tloc = tid & 63, qg = tid >> 6;
  float acc[9];
  #pragma unroll
  for (int i = 0; i < 9; ++i) acc[i] = 0.f;
  const float* capglo = ws + WS_CAPGLO;
  const float* imgglo = ws + WS_IMGGLO + (size_t)v * CDIM;

  for (int ct = 0; ct < 8; ++ct) {
    for (int i = tid; i < 33 * 64; i += 256) {
      int q = i >> 6, cc = i & 63;
      qt[i] = (q < 32) ? capglo[(size_t)q * CDIM + ct * 64 + cc] : imgglo[ct * 64 + cc];
    }
    for (int i = tid; i < 64 * 64; i += 256) {
      int tok = i >> 6, cc = i & 63;
      int l = t0 + tok;
      xt[tok * 65 + cc] = (l < LV) ? img[((size_t)v * LV + l) * CDIM + ct * 64 + cc] : 0.f;
    }
    __syncthreads();
    for (int cc = 0; cc < 64; ++cc) {
      float xv = xt[tloc * 65 + cc];
      #pragma unroll
      for (int qi = 0; qi < 9; ++qi) {
        int q = qg + 4 * qi;
        if (q < 33) acc[qi] += qt[q * 64 + cc] * xv;
      }
    }
    __syncthreads();
  }
  if (qg == 0) dself[tloc] = acc[8];
  __syncthreads();
  int l = t0 + tloc;
  if (l < LV) {
    float invn = ws[WS_INVN + (size_t)v * LV + l];
    float ds = dself[tloc];
    #pragma unroll
    for (int qi = 0; qi < 9; ++qi) {
      int q = qg + 4 * qi;
      if (q < 32) ws[WS_SCORE + ((size_t)q * BV + v) * LV + l] = (acc[qi] + ds) * invn;
    }
  }
}

// ---------------------------------------------------------------------------
// K4 (R8): verbatim R5 k4 (which passed at 291 us), templated on USE_IMGT.
// USE_IMGT=0: byte-for-byte the R5 version (LDS token staging K-loop).
// USE_IMGT=1: ONLY P5 differs -- B-fragments read directly from global imgT
// (bf16 token-major, written by k0). Removes 14 staging barriers + staging
// bank conflicts. Everything else (layout, zeroing, P6-P10) is R5-identical.
// ---------------------------------------------------------------------------
template<int USE_IMGT>
__global__ __launch_bounds__(512, 2) void k4_main(const float* __restrict__ img,
                                                  const float* __restrict__ scale_p,
                                                  const float* __restrict__ ws,
                                                  float* __restrict__ out) {
  __shared__ float s_sc[LV];
  __shared__ int   s_kidx[NKEEP];
  __shared__ int   s_nidx[NNON];
  __shared__ int   s_cnt[2];
  __shared__ float s_wk[NNON];
  __shared__ float s_red[128];
  __shared__ float s_pool2[64];
  __shared__ float s_inv[64];
  __shared__ __align__(16) __hip_bfloat16 s_selh[64 * SEL_STR];  // 66.6 KB
  __shared__ __align__(16) __hip_bfloat16 s_wa[64 * WA_STR];     // 29.7 KB; later sims+G
  __shared__ __align__(16) __hip_bfloat16 s_dyn[512 * TOK_STR];  // 41 KB; s_w / tok / cap

  float* s_w = (float*)s_dyn;                       // 49*98 f32 = 19.2 KB
  __hip_bfloat16* s_tok = s_dyn;                    // [512 c][TOK_STR]
  __hip_bfloat16* s_cap = s_dyn;                    // [32 w][SEL_STR] = 33.3 KB
  float* s_sims = (float*)s_wa;                     // [32 w][64 p] f32 = 8 KB
  float* s_G = (float*)((char*)s_wa + 8192);        // [64][G_STR] f32 = 16.9 KB

  int b = blockIdx.x;
  int v = b >> 5, t = b & 31;
  int tid = threadIdx.x;
  int wv = tid >> 6, lane = tid & 63;
  int quad = lane >> 4, l15 = lane & 15;
  int koff = quad * 8;

  // ---- P0: loads + zero-init ----
  if (tid < 2) s_cnt[tid] = 0;
  if (tid < 64) s_pool2[tid] = 0.f;
  if (tid < LV) s_sc[tid] = ws[WS_SCORE + ((size_t)t * BV + v) * LV + tid];
  {
    uint* za = (uint*)s_wa;                         // zero full A matrix
    for (int i = tid; i < 64 * WA_STR / 2; i += 512) za[i] = 0u;
    uint* zs = (uint*)(s_selh + 50 * SEL_STR);      // zero sel rows 50..63
    for (int i = tid; i < 14 * SEL_STR / 2; i += 512) zs[i] = 0u;
  }
  __syncthreads();

  // ---- P1: rank & partition (stable argsort of -score semantics) ----
  if (tid < LV) {
    float my = s_sc[tid];
    int cnt = 0;
    for (int j = 0; j < LV; ++j) {
      float sj = s_sc[j];
      cnt += (sj > my) || (sj == my && j < tid);
    }
    bool keep = cnt < NKEEP;
    out[BV * BT + ((size_t)t * BV + v) * LV + tid] = keep ? 1.f : 0.f;
    if (keep) { int p = atomicAdd(&s_cnt[0], 1); s_kidx[p] = tid; }
    else      { int p = atomicAdd(&s_cnt[1], 1); s_nidx[p] = tid; }
  }
  __syncthreads();

  // ---- P2: softmax over non-kept scores -> s_wk ----
  if (tid < 128) s_red[tid] = (tid < NNON) ? s_sc[s_nidx[tid]] : -3.0e38f;
  __syncthreads();
  for (int off = 64; off > 0; off >>= 1) {
    if (tid < off) s_red[tid] = fmaxf(s_red[tid], s_red[tid + off]);
    __syncthreads();
  }
  float nm = s_red[0];
  __syncthreads();
  float e0 = 0.f;
  if (tid < NNON) e0 = expf(s_sc[s_nidx[tid]] - nm);
  if (tid < 128) s_red[tid] = (tid < NNON) ? e0 : 0.f;
  __syncthreads();
  for (int off = 64; off > 0; off >>= 1) {
    if (tid < off) s_red[tid] += s_red[tid + off];
    __syncthreads();
  }
  float nS = s_red[0];
  __syncthreads();
  if (tid < NNON) s_wk[tid] = e0 / nS;
  __syncthreads();

  // ---- P3: wlog gather -> s_w[p][r] fp32, softmax over r per pool ----
  float scale_val = scale_p[0];
  for (int i = tid; i < KEEPED * NKEEP; i += 512) {
    int k = i / KEEPED, p = i - k * KEEPED;
    s_w[p * NKEEP + k] = ws[WS_WLOG + ((size_t)v * LV + s_kidx[k]) * KEEPED + p] * scale_val;
  }
  __syncthreads();
  if (tid < KEEPED * 8) {
    int p = tid >> 3, g = tid & 7;
    float mm = -3e38f;
    for (int k = g; k < NKEEP; k += 8) mm = fmaxf(mm, s_w[p * NKEEP + k]);
    #pragma unroll
    for (int off = 4; off > 0; off >>= 1) mm = fmaxf(mm, __shfl_xor(mm, off, 8));
    float ss = 0.f;
    for (int k = g; k < NKEEP; k += 8) {
      float ee = expf(s_w[p * NKEEP + k] - mm);
      s_w[p * NKEEP + k] = ee;
      ss += ee;
    }
    #pragma unroll
    for (int off = 4; off > 0; off >>= 1) ss += __shfl_xor(ss, off, 8);
    float rs = 1.f / ss;
    for (int k = g; k < NKEEP; k += 8) s_w[p * NKEEP + k] *= rs;
  }
  __syncthreads();

  // ---- P4: scatter A = s_wa (bf16): kept weights + wk row 49 ----
  for (int i = tid; i < KEEPED * NKEEP; i += 512) {
    int p = i / NKEEP, r = i - p * NKEEP;
    s_wa[p * WA_STR + s_kidx[r]] = __float2bfloat16(s_w[p * NKEEP + r]);
  }
  if (tid < NNON) s_wa[49 * WA_STR + s_nidx[tid]] = __float2bfloat16(s_wk[tid]);
  __syncthreads();   // s_dyn repurposed next (staged path) / s_wa ready

  // ---- P5: aggr GEMM, K-loop of 7 x 32 tokens ----
  v4f acc[4][4];   // [mtile][ntile-local]; wave owns channels [wv*64, wv*64+64)
  #pragma unroll
  for (int m = 0; m < 4; ++m)
    #pragma unroll
    for (int j = 0; j < 4; ++j) acc[m][j] = (v4f){0.f, 0.f, 0.f, 0.f};

  if (USE_IMGT) {
    const __hip_bfloat16* imgTv =
        (const __hip_bfloat16*)((const char*)ws + WS_IMGT_B) + (size_t)v * CDIM * TOKPAD;
    for (int ks = 0; ks < 7; ++ks) {
      v8s bfr[4];
      #pragma unroll
      for (int j = 0; j < 4; ++j)
        bfr[j] = *(const v8s*)(imgTv + (size_t)(wv * 64 + j * 16 + l15) * TOKPAD + ks * 32 + koff);
      #pragma unroll
      for (int m = 0; m < 4; ++m) {
        v8s af = *(const v8s*)(s_wa + (m * 16 + l15) * WA_STR + ks * 32 + koff);
        #pragma unroll
        for (int j = 0; j < 4; ++j) acc[m][j] = MFMA16(af, bfr[j], acc[m][j]);
      }
    }
  } else {
    for (int ks = 0; ks < 7; ++ks) {
      // stage 32 tokens channel-major bf16: s_tok[c][kl] = img[v][ks*32+kl][c]
      #pragma unroll
      for (int it = 0; it < 8; ++it) {
        int k0 = ks * 32 + it * 4;
        if (k0 < LV) {   // LV divisible by 4 -> all 4 valid
          const float* gp = img + ((size_t)v * LV + k0) * CDIM + tid;
          float x0 = gp[0], x1 = gp[CDIM], x2 = gp[2 * CDIM], x3 = gp[3 * CDIM];
          union { __hip_bfloat16 h[4]; uint2 u; } pk;
          pk.h[0] = __float2bfloat16(x0); pk.h[1] = __float2bfloat16(x1);
          pk.h[2] = __float2bfloat16(x2); pk.h[3] = __float2bfloat16(x3);
          *(uint2*)(s_tok + tid * TOK_STR + it * 4) = pk.u;
        }
      }
      __syncthreads();
      v8s bfr[4];
      #pragma unroll
      for (int j = 0; j < 4; ++j)
        bfr[j] = *(const v8s*)(s_tok + (wv * 64 + j * 16 + l15) * TOK_STR + koff);
      #pragma unroll
      for (int m = 0; m < 4; ++m) {
        v8s af = *(const v8s*)(s_wa + (m * 16 + l15) * WA_STR + ks * 32 + koff);
        #pragma unroll
        for (int j = 0; j < 4; ++j) acc[m][j] = MFMA16(af, bfr[j], acc[m][j]);
      }
      __syncthreads();
    }
  }

  // ---- P6: cap staging (s_dyn free now) + pool l2norm ----
  if (!USE_IMGT) __syncthreads();   // staged path: ensure last MFMA reads done
  for (int i = tid; i < NW * 128; i += 512) {     // 24 w x 128 quads
    int w = i >> 7, cq = i & 127;
    const float4 xv = *(const float4*)(ws + WS_CAPNORM + ((size_t)t * NW + w) * CDIM + cq * 4);
    union { __hip_bfloat16 h[4]; uint2 u; } pk;
    pk.h[0] = __float2bfloat16(xv.x); pk.h[1] = __float2bfloat16(xv.y);
    pk.h[2] = __float2bfloat16(xv.z); pk.h[3] = __float2bfloat16(xv.w);
    *(uint2*)(s_cap + w * SEL_STR + cq * 4) = pk.u;
  }
  {
    uint* zc = (uint*)(s_cap + 24 * SEL_STR);     // zero cap rows 24..31
    for (int i = tid; i < 8 * SEL_STR / 2; i += 512) zc[i] = 0u;
  }
  #pragma unroll
  for (int m = 0; m < 4; ++m) {
    #pragma unroll
    for (int reg = 0; reg < 4; ++reg) {
      float ss = acc[m][0][reg] * acc[m][0][reg] + acc[m][1][reg] * acc[m][1][reg]
               + acc[m][2][reg] * acc[m][2][reg] + acc[m][3][reg] * acc[m][3][reg];
      #pragma unroll
      for (int off = 8; off > 0; off >>= 1) ss += __shfl_xor(ss, off, 64);  // over l15
      if (l15 == 0) atomicAdd(&s_pool2[m * 16 + quad * 4 + reg], ss);
    }
  }
  __syncthreads();
  if (tid < 64) s_inv[tid] = 1.f / fmaxf(sqrtf(s_pool2[tid]), 1e-12f);
  __syncthreads();
  #pragma unroll
  for (int m = 0; m < 4; ++m) {
    #pragma unroll
    for (int reg = 0; reg < 4; ++reg) {
      int p = m * 16 + quad * 4 + reg;
      if (p < 50) {
        float iv = s_inv[p];
        #pragma unroll
        for (int j = 0; j < 4; ++j)
          s_selh[p * SEL_STR + wv * 64 + j * 16 + l15] = __float2bfloat16(acc[m][j][reg] * iv);
      }
    }
  }
  __syncthreads();

  // ---- P7: sims = cap . sel^T via MFMA; one 16x16 tile per wave ----
  {
    int mt = wv >> 2, nt = wv & 3;
    v4f sa = (v4f){0.f, 0.f, 0.f, 0.f};
    for (int ks = 0; ks < 16; ++ks) {
      v8s a = *(const v8s*)(s_cap + (mt * 16 + l15) * SEL_STR + ks * 32 + koff);
      v8s bb = *(const v8s*)(s_selh + (nt * 16 + l15) * SEL_STR + ks * 32 + koff);
      sa = MFMA16(a, bb, sa);
    }
    #pragma unroll
    for (int reg = 0; reg < 4; ++reg)
      s_sims[(mt * 16 + quad * 4 + reg) * 64 + nt * 16 + l15] = sa[reg];
  }
  __syncthreads();

  // ---- P8: per-word softmax (unnormalized e) + num = sum e*s ----
  if (tid < NW * 8) {
    int w = tid >> 3, g = tid & 7;
    float* row = s_sims + w * 64;
    float mm = -3e38f;
    for (int p = g; p < 50; p += 8) mm = fmaxf(mm, row[p]);
    #pragma unroll
    for (int off = 4; off > 0; off >>= 1) mm = fmaxf(mm, __shfl_xor(mm, off, 8));
    float num = 0.f;
    for (int p = g; p < 64; p += 8) {
      if (p < 50) {
        float s = row[p];
        float ee = expf(LAMBDA_ * (s - mm));
        num += ee * s;
        row[p] = ee;
      } else row[p] = 0.f;
    }
    #pragma unroll
    for (int off = 4; off > 0; off >>= 1) num += __shfl_xor(num, off, 8);
    if (g == 0) s_red[w] = num;
  }
  __syncthreads();

  // ---- P9: G = sel . sel^T via MFMA; 2 tiles per wave ----
  #pragma unroll
  for (int i2 = 0; i2 < 2; ++i2) {
    int idx = wv * 2 + i2;
    int gm = idx >> 2, gn = idx & 3;
    v4f ga = (v4f){0.f, 0.f, 0.f, 0.f};
    for (int ks = 0; ks < 16; ++ks) {
      v8s a = *(const v8s*)(s_selh + (gm * 16 + l15) * SEL_STR + ks * 32 + koff);
      v8s bb = *(const v8s*)(s_selh + (gn * 16 + l15) * SEL_STR + ks * 32 + koff);
      ga = MFMA16(a, bb, ga);
    }
    #pragma unroll
    for (int reg = 0; reg < 4; ++reg)
      s_G[(gm * 16 + quad * 4 + reg) * G_STR + gn * 16 + l15] = ga[reg];
  }
  __syncthreads();

  // ---- P10: word_sim = num / sqrt(e^T G e); mean over words ----
  float wacc = 0.f;
  for (int w = wv; w < NW; w += 8) {
    const float* ev = s_sims + w * 64;
    float tl = 0.f;
    for (int q = 0; q < 50; ++q) tl += s_G[q * G_STR + lane] * ev[q];
    float ql = ev[lane] * tl;
    #pragma unroll
    for (int off = 32; off > 0; off >>= 1) ql += __shfl_xor(ql, off, 64);
    if (lane == 0) wacc += s_red[w] / fmaxf(sqrtf(ql), 1e-20f);
  }
  if (lane == 0) s_red[64 + wv] = wacc;
  __syncthreads();
  if (tid == 0) {
    float s = 0.f;
    #pragma unroll
    for (int i = 0; i < 8; ++i) s += s_red[64 + i];
    out[(size_t)v * BT + t] = s / (float)NW;   // improve_sims = sim.T
  }
}

// ---------------------------------------------------------------------------
extern "C" void kernel_launch(void* const* d_in, const int* in_sizes, int n_in,
                              void* d_out, int out_size, void* d_ws, size_t ws_size,
                              hipStream_t stream) {
  const float* img   = (const float*)d_in[0];
  const float* cap   = (const float*)d_in[1];
  // d_in[2] = cap_lens (unused by forward)
  const float* gamma = (const float*)d_in[3];
  const float* beta  = (const float*)d_in[4];
  const float* W1    = (const float*)d_in[5];
  const float* b1    = (const float*)d_in[6];
  const float* W2    = (const float*)d_in[7];
  const float* b2    = (const float*)d_in[8];
  const float* scale = (const float*)d_in[9];
  float* ws  = (float*)d_ws;
  float* out = (float*)d_out;

  const bool big = (ws_size >= WS_NEED_B);   // constant across calls -> graph-safe

  if (big) k0_prep<<<dim3(BV, 7), dim3(512), 0, stream>>>(img, ws);
  k1_glo <<<dim3(BT + BV), dim3(256), 0, stream>>>(img, cap, ws);
  k2_token<<<dim3(BV, (LV + TOK - 1) / TOK), dim3(256), 0, stream>>>(img, gamma, beta, W1, b1, W2, b2, ws);
  k3_score<<<dim3(BV, 4), dim3(256), 0, stream>>>(img, ws);
  if (big) k4_main<1><<<dim3(BV * BT), dim3(512), 0, stream>>>(img, scale, ws, out);
  else     k4_main<0><<<dim3(BV * BT), dim3(512), 0, stream>>>(img, scale, ws, out);
}

// Round 9
// 512.727 us; speedup vs baseline: 4.2531x; 1.2795x over previous
//
#include <hip/hip_runtime.h>
#include <hip/hip_bf16.h>
#include <math.h>

#define CDIM 512
#define LV 196
#define BV 64
#define BT 32
#define NW 24
#define NKEEP 98
#define NNON 98      // LV - NKEEP
#define KEEPED 49
#define HID 102
#define LAMBDA_ 4.0f
#define LN_EPS_ 1e-5f

// ws layout (float offsets)
#define WS_CAPNORM 0
#define WS_CAPGLO  (WS_CAPNORM + BT*NW*CDIM)     // 393216
#define WS_IMGGLO  (WS_CAPGLO + BT*CDIM)         // +16384
#define WS_INVN    (WS_IMGGLO + BV*CDIM)         // +32768
#define WS_WLOG    (WS_INVN + BV*LV)             // +12544
#define WS_SCORE   (WS_WLOG + BV*LV*KEEPED)      // +614656
#define WS_END     (WS_SCORE + BT*BV*LV)         // 1470976 floats = 5.88 MB
// imgT (big path only): bf16 [64][512][224] appended after WS_END
#define WS_IMGT_B  ((size_t)WS_END * 4)          // byte offset 5883904
#define TOKPAD 224
#define WS_NEED_B  (WS_IMGT_B + (size_t)BV * CDIM * TOKPAD * 2)   // 20563968 B
// W1T/W2T (bf16) live in the WS_SCORE region: written by k5_prep, read by k2,
// then SCORE is overwritten by k3 (stream-ordered). 129 KB << 1.6 MB region.
#define WS_W1T_B   ((size_t)WS_SCORE * 4)
#define WS_W2T_B   (WS_W1T_B + (size_t)112 * 512 * 2)

typedef short v8s __attribute__((ext_vector_type(8)));   // 8 bf16 (4 VGPR)
typedef float v4f __attribute__((ext_vector_type(4)));
#define MFMA16(a, b, c) __builtin_amdgcn_mfma_f32_16x16x32_bf16((a), (b), (c), 0, 0, 0)

// LDS strides (elements), padded for bank behavior + alignment:
#define WA_STR 232    // A matrix rows (464 B, 16-aligned, 2-way banks)
#define TOK_STR 40    // token K-tile rows (80 B, 16-aligned)
#define SEL_STR 520   // sel rows (1040 B, 16-aligned, 2-way banks)
#define G_STR 66      // Gram rows (f32)
#define XN_STR 520    // k2 xn rows (bf16)
#define HB_STR 136    // k2 hbuf rows (bf16; 136=2-way banks, not pow2)

__device__ __forceinline__ ushort bfb(float f) {
  __hip_bfloat16 h = __float2bfloat16(f);
  union { __hip_bfloat16 h; ushort u; } cv; cv.h = h; return cv.u;
}

// ---------------------------------------------------------------------------
// K0 (big path only): imgT[v][c][tok] bf16, tok padded 196->224 with zeros.
// (verbatim R8-passing version)
// ---------------------------------------------------------------------------
__global__ __launch_bounds__(512) void k0_prep(const float* __restrict__ img,
                                               float* __restrict__ ws) {
  int v = blockIdx.x, kt = blockIdx.y, c = threadIdx.x;
  float x[32];
  #pragma unroll
  for (int kk = 0; kk < 32; ++kk) {
    int tok = kt * 32 + kk;
    x[kk] = (tok < LV) ? img[((size_t)v * LV + tok) * CDIM + c] : 0.f;
  }
  __hip_bfloat16* imgT = (__hip_bfloat16*)((char*)ws + WS_IMGT_B);
  uint* dst = (uint*)(imgT + ((size_t)v * CDIM + c) * TOKPAD + kt * 32);
  #pragma unroll
  for (int g = 0; g < 4; ++g) {
    uint4 u;
    u.x = (uint)bfb(x[g*8+0]) | ((uint)bfb(x[g*8+1]) << 16);
    u.y = (uint)bfb(x[g*8+2]) | ((uint)bfb(x[g*8+3]) << 16);
    u.z = (uint)bfb(x[g*8+4]) | ((uint)bfb(x[g*8+5]) << 16);
    u.w = (uint)bfb(x[g*8+6]) | ((uint)bfb(x[g*8+7]) << 16);
    *(uint4*)(dst + g * 4) = u;
  }
}

// ---------------------------------------------------------------------------
// K5: transpose W1 -> W1T bf16 [112 h][512 k], W2 -> W2T bf16 [64 p][128 h]
// into the WS_SCORE region (dead until k3). Pads zeroed.
// grid 176: blocks 0..111 = W1T rows; 112..175 = W2T rows.
// ---------------------------------------------------------------------------
__global__ __launch_bounds__(512) void k5_prep(const float* __restrict__ W1,
                                               const float* __restrict__ W2,
                                               float* __restrict__ ws) {
  int b = blockIdx.x, tid = threadIdx.x;
  if (b < 112) {
    int h = b;
    float val = (h < HID) ? W1[(size_t)tid * HID + h] : 0.f;
    ((ushort*)((char*)ws + WS_W1T_B))[(size_t)h * 512 + tid] = bfb(val);
  } else {
    int p = b - 112;
    if (tid < 128) {
      int h = tid;
      float val = (p < KEEPED && h < HID) ? W2[(size_t)h * KEEPED + p] : 0.f;
      ((ushort*)((char*)ws + WS_W2T_B))[(size_t)p * 128 + h] = bfb(val);
    }
  }
}

// ---------------------------------------------------------------------------
// K1: cap_norm + cap_glo (blocks 0..31, wave-per-word, 9 barriers instead of
// ~200), img_glo (blocks 32..95, verbatim R8). 256 thr.
// ---------------------------------------------------------------------------
__global__ __launch_bounds__(256) void k1_glo(const float* __restrict__ img,
                                              const float* __restrict__ cap,
                                              float* __restrict__ ws) {
  __shared__ float red[256];
  __shared__ float s_part[4 * CDIM];   // per-wave raw-sum partials
  __shared__ float s_glo[CDIM];
  int b = blockIdx.x, tid = threadIdx.x;
  if (b < BT) {
    int t = b;
    int wv = tid >> 6, lane = tid & 63;
    int cb = lane * 8;
    float4 sA = make_float4(0.f,0.f,0.f,0.f), sB = make_float4(0.f,0.f,0.f,0.f);
    for (int w = wv; w < NW; w += 4) {
      const float* p = cap + ((size_t)t * NW + w) * CDIM + cb;
      float4 xa = *(const float4*)p;
      float4 xb = *(const float4*)(p + 4);
      float ss = xa.x*xa.x + xa.y*xa.y + xa.z*xa.z + xa.w*xa.w
               + xb.x*xb.x + xb.y*xb.y + xb.z*xb.z + xb.w*xb.w;
      #pragma unroll
      for (int off = 32; off > 0; off >>= 1) ss += __shfl_xor(ss, off, 64);
      float inv = 1.f / fmaxf(sqrtf(ss), 1e-12f);
      float* q = ws + WS_CAPNORM + ((size_t)t * NW + w) * CDIM + cb;
      *(float4*)q       = make_float4(xa.x*inv, xa.y*inv, xa.z*inv, xa.w*inv);
      *(float4*)(q + 4) = make_float4(xb.x*inv, xb.y*inv, xb.z*inv, xb.w*inv);
      sA.x += xa.x; sA.y += xa.y; sA.z += xa.z; sA.w += xa.w;
      sB.x += xb.x; sB.y += xb.y; sB.z += xb.z; sB.w += xb.w;
    }
    *(float4*)&s_part[wv * CDIM + cb]     = sA;
    *(float4*)&s_part[wv * CDIM + cb + 4] = sB;
    __syncthreads();
    if (tid < 128) {
      float4 g = make_float4(0.f, 0.f, 0.f, 0.f);
      #pragma unroll
      for (int w2 = 0; w2 < 4; ++w2) {
        float4 pv = *(const float4*)&s_part[w2 * CDIM + tid * 4];
        g.x += pv.x; g.y += pv.y; g.z += pv.z; g.w += pv.w;
      }
      g.x /= (float)NW; g.y /= (float)NW; g.z /= (float)NW; g.w /= (float)NW;
      *(float4*)&s_glo[tid * 4] = g;
      red[tid] = g.x*g.x + g.y*g.y + g.z*g.z + g.w*g.w;
    }
    __syncthreads();
    for (int off = 64; off > 0; off >>= 1) {
      if (tid < off) red[tid] += red[tid + off];
      __syncthreads();
    }
    float inv = 1.f / fmaxf(sqrtf(red[0]), 1e-12f);
    if (tid < 128) {
      float4 g = *(const float4*)&s_glo[tid * 4];
      *(float4*)(ws + WS_CAPGLO + (size_t)t * CDIM + tid * 4) =
          make_float4(g.x*inv, g.y*inv, g.z*inv, g.w*inv);
    }
  } else {
    // verbatim R8 img branch
    int c0 = tid, c1 = tid + 256;
    int v = b - BT;
    float s0 = 0.f, s1 = 0.f;
    const float* base = img + (size_t)v * LV * CDIM;
    for (int l = 0; l < LV; ++l) { s0 += base[l * CDIM + c0]; s1 += base[l * CDIM + c1]; }
    float g0 = s0 / (float)LV, g1 = s1 / (float)LV;
    red[tid] = g0 * g0 + g1 * g1;
    __syncthreads();
    for (int off = 128; off > 0; off >>= 1) {
      if (tid < off) red[tid] += red[tid + off];
      __syncthreads();
    }
    float inv = 1.f / fmaxf(sqrtf(red[0]), 1e-12f);
    float* q = ws + WS_IMGGLO + (size_t)v * CDIM;
    q[c0] = g0 * inv; q[c1] = g1 * inv;
  }
}

// ---------------------------------------------------------------------------
// K2 (R9): MFMA MLP. grid (64 v, 2 halves), 512 thr (8 waves).
// Phase A: wave-per-token LN -> xn bf16 LDS [112][520] (+ invn to ws).
// GEMM1: C1[112 tok][112 h] = xn @ W1T^T (A from LDS, B from global W1T).
// gelu+bias -> hbuf bf16 [112][136] (overlays xn after barrier; cols>=102
// written 0, cols 112..127 zeroed -> K=128 pad safe).
// GEMM2: C2[112 tok][64 p] = hbuf @ W2T^T -> wlog (+b2), masked tok<98,p<49.
// Pad-row garbage flows only into masked-out C rows (NaN never escapes).
// ---------------------------------------------------------------------------
__global__ __launch_bounds__(512, 2) void k2_mlp(const float* __restrict__ img,
                                                 const float* __restrict__ gamma,
                                                 const float* __restrict__ beta,
                                                 const float* __restrict__ b1,
                                                 const float* __restrict__ b2,
                                                 float* __restrict__ ws) {
  __shared__ __align__(16) __hip_bfloat16 s_xn[112 * XN_STR];  // 116,480 B
  __hip_bfloat16* s_hb = s_xn;                                 // overlay after GEMM1

  int v = blockIdx.x, half = blockIdx.y;
  int l0 = half * 98;
  int tid = threadIdx.x, wv = tid >> 6, lane = tid & 63;
  int quad = lane >> 4, l15 = lane & 15, koff = quad * 8;
  const __hip_bfloat16* W1T = (const __hip_bfloat16*)((const char*)ws + WS_W1T_B);
  const __hip_bfloat16* W2T = (const __hip_bfloat16*)((const char*)ws + WS_W2T_B);

  // ---- Phase A: LN -> xn bf16 ----
  int cb = lane * 8;
  float4 g4a = *(const float4*)(gamma + cb);
  float4 g4b = *(const float4*)(gamma + cb + 4);
  float4 b4a = *(const float4*)(beta + cb);
  float4 b4b = *(const float4*)(beta + cb + 4);
  for (int tok = wv; tok < 98; tok += 8) {
    const float* p = img + ((size_t)v * LV + l0 + tok) * CDIM + cb;
    float4 xa = *(const float4*)p;
    float4 xb = *(const float4*)(p + 4);
    float s  = xa.x + xa.y + xa.z + xa.w + xb.x + xb.y + xb.z + xb.w;
    float sq = xa.x*xa.x + xa.y*xa.y + xa.z*xa.z + xa.w*xa.w
             + xb.x*xb.x + xb.y*xb.y + xb.z*xb.z + xb.w*xb.w;
    #pragma unroll
    for (int off = 32; off > 0; off >>= 1) { s += __shfl_xor(s, off, 64); sq += __shfl_xor(sq, off, 64); }
    float mean = s / (float)CDIM;
    float var = sq / (float)CDIM - mean * mean;
    float rstd = 1.f / sqrtf(var + LN_EPS_);
    if (lane == 0) ws[WS_INVN + (size_t)v * LV + l0 + tok] = 1.f / fmaxf(sqrtf(sq), 1e-12f);
    float f[8];
    f[0] = (xa.x - mean) * rstd * g4a.x + b4a.x;
    f[1] = (xa.y - mean) * rstd * g4a.y + b4a.y;
    f[2] = (xa.z - mean) * rstd * g4a.z + b4a.z;
    f[3] = (xa.w - mean) * rstd * g4a.w + b4a.w;
    f[4] = (xb.x - mean) * rstd * g4b.x + b4b.x;
    f[5] = (xb.y - mean) * rstd * g4b.y + b4b.y;
    f[6] = (xb.z - mean) * rstd * g4b.z + b4b.z;
    f[7] = (xb.w - mean) * rstd * g4b.w + b4b.w;
    uint4 u;
    u.x = (uint)bfb(f[0]) | ((uint)bfb(f[1]) << 16);
    u.y = (uint)bfb(f[2]) | ((uint)bfb(f[3]) << 16);
    u.z = (uint)bfb(f[4]) | ((uint)bfb(f[5]) << 16);
    u.w = (uint)bfb(f[6]) | ((uint)bfb(f[7]) << 16);
    *(uint4*)(s_xn + (size_t)tok * XN_STR + cb) = u;
  }
  __syncthreads();

  // ---- GEMM1: tiles idx = wv + 8*i (i<7), mt = idx/7, nt = idx%7 ----
  v4f c1[7];
  int mt_[7], nt_[7];
  #pragma unroll
  for (int i = 0; i < 7; ++i) {
    int idx = wv + 8 * i; if (idx > 48) idx = 48;   // clamp: keep reads in-bounds
    mt_[i] = idx / 7; nt_[i] = idx % 7;
    c1[i] = (v4f){0.f, 0.f, 0.f, 0.f};
  }
  for (int ks = 0; ks < 16; ++ks) {
    #pragma unroll
    for (int i = 0; i < 7; ++i) {
      v8s a  = *(const v8s*)(s_xn + (size_t)(mt_[i] * 16 + l15) * XN_STR + ks * 32 + koff);
      v8s bb = *(const v8s*)(W1T + (size_t)(nt_[i] * 16 + l15) * 512 + ks * 32 + koff);
      c1[i] = MFMA16(a, bb, c1[i]);
    }
  }
  __syncthreads();   // all xn reads complete before hbuf overlay

  // ---- gelu + bias -> hbuf ----
  #pragma unroll
  for (int i = 0; i < 7; ++i) {
    int idx = wv + 8 * i;
    if (idx < 49) {
      int h = nt_[i] * 16 + l15;
      float bias = (h < HID) ? b1[h] : 0.f;
      #pragma unroll
      for (int reg = 0; reg < 4; ++reg) {
        int row = mt_[i] * 16 + quad * 4 + reg;
        float x = c1[i][reg] + bias;
        float gl = (h < HID) ? 0.5f * x * (1.f + erff(x * 0.70710678118654752f)) : 0.f;
        s_hb[(size_t)row * HB_STR + h] = __float2bfloat16(gl);
      }
    }
  }
  for (int i = tid; i < 112 * 16; i += 512)   // zero cols 112..127 (K pad)
    s_hb[(size_t)(i >> 4) * HB_STR + 112 + (i & 15)] = __float2bfloat16(0.f);
  __syncthreads();

  // ---- GEMM2: tiles idx = wv + 8*i (i<4), m2 = idx/4, n2 = idx%4, K=128 ----
  v4f c2[4];
  int m2_[4], n2_[4];
  #pragma unroll
  for (int i = 0; i < 4; ++i) {
    int idx = wv + 8 * i;
    m2_[i] = idx / 4; n2_[i] = idx % 4;   // idx<=31 -> rows <=127, in-bounds
    c2[i] = (v4f){0.f, 0.f, 0.f, 0.f};
  }
  for (int ks = 0; ks < 4; ++ks) {
    #pragma unroll
    for (int i = 0; i < 4; ++i) {
      v8s a  = *(const v8s*)(s_hb + (size_t)(m2_[i] * 16 + l15) * HB_STR + ks * 32 + koff);
      v8s bb = *(const v8s*)(W2T + (size_t)(n2_[i] * 16 + l15) * 128 + ks * 32 + koff);
      c2[i] = MFMA16(a, bb, c2[i]);
    }
  }
  #pragma unroll
  for (int i = 0; i < 4; ++i) {
    int idx = wv + 8 * i;
    if (idx < 28) {
      int p = n2_[i] * 16 + l15;
      if (p < KEEPED) {
        float bias = b2[p];
        #pragma unroll
        for (int reg = 0; reg < 4; ++reg) {
          int tok = m2_[i] * 16 + quad * 4 + reg;
          if (tok < 98)
            ws[WS_WLOG + ((size_t)v * LV + l0 + tok) * KEEPED + p] = c2[i][reg] + bias;
        }
      }
    }
  }
}

// ---------------------------------------------------------------------------
// K3: scores. (verbatim R8)
// ---------------------------------------------------------------------------
__global__ __launch_bounds__(256) void k3_score(const float* __restrict__ img,
                                                float* __restrict__ ws) {
  __shared__ float qt[33 * 64];
  __shared__ float xt[64 * 65];
  __shared__ float dself[64];
  int v = blockIdx.x;
  int t0 = blockIdx.y * 64;
  int tid = threadIdx.x;
  int tloc = tid & 63, qg = tid >> 6;
  float acc[9];
  #pragma unroll
  for (int i = 0; i < 9; ++i) acc[i] = 0.f;
  const float* capglo = ws + WS_CAPGLO;
  const float* imgglo = ws + WS_IMGGLO + (size_t)v * CDIM;

  for (int ct = 0; ct < 8; ++ct) {
    for (int i = tid; i < 33 * 64; i += 256) {
      int q = i >> 6, cc = i & 63;
      qt[i] = (q < 32) ? capglo[(size_t)q * CDIM + ct * 64 + cc] : imgglo[ct * 64 + cc];
    }
    for (int i = tid; i < 64 * 64; i += 256) {
      int tok = i >> 6, cc = i & 63;
      int l = t0 + tok;
      xt[tok * 65 + cc] = (l < LV) ? img[((size_t)v * LV + l) * CDIM + ct * 64 + cc] : 0.f;
    }
    __syncthreads();
    for (int cc = 0; cc < 64; ++cc) {
      float xv = xt[tloc * 65 + cc];
      #pragma unroll
      for (int qi = 0; qi < 9; ++qi) {
        int q = qg + 4 * qi;
        if (q < 33) acc[qi] += qt[q * 64 + cc] * xv;
      }
    }
    __syncthreads();
  }
  if (qg == 0) dself[tloc] = acc[8];
  __syncthreads();
  int l = t0 + tloc;
  if (l < LV) {
    float invn = ws[WS_INVN + (size_t)v * LV + l];
    float ds = dself[tloc];
    #pragma unroll
    for (int qi = 0; qi < 9; ++qi) {
      int q = qg + 4 * qi;
      if (q < 32) ws[WS_SCORE + ((size_t)q * BV + v) * LV + l] = (acc[qi] + ds) * invn;
    }
  }
}

// ---------------------------------------------------------------------------
// K4: verbatim R8 (green at 240 us). USE_IMGT=1: B-frags from global imgT.
// USE_IMGT=0: R5 LDS-staging path.
// ---------------------------------------------------------------------------
template<int USE_IMGT>
__global__ __launch_bounds__(512, 2) void k4_main(const float* __restrict__ img,
                                                  const float* __restrict__ scale_p,
                                                  const float* __restrict__ ws,
                                                  float* __restrict__ out) {
  __shared__ float s_sc[LV];
  __shared__ int   s_kidx[NKEEP];
  __shared__ int   s_nidx[NNON];
  __shared__ int   s_cnt[2];
  __shared__ float s_wk[NNON];
  __shared__ float s_red[128];
  __shared__ float s_pool2[64];
  __shared__ float s_inv[64];
  __shared__ __align__(16) __hip_bfloat16 s_selh[64 * SEL_STR];  // 66.6 KB
  __shared__ __align__(16) __hip_bfloat16 s_wa[64 * WA_STR];     // 29.7 KB; later sims+G
  __shared__ __align__(16) __hip_bfloat16 s_dyn[512 * TOK_STR];  // 41 KB; s_w / tok / cap

  float* s_w = (float*)s_dyn;
  __hip_bfloat16* s_tok = s_dyn;
  __hip_bfloat16* s_cap = s_dyn;
  float* s_sims = (float*)s_wa;
  float* s_G = (float*)((char*)s_wa + 8192);

  int b = blockIdx.x;
  int v = b >> 5, t = b & 31;
  int tid = threadIdx.x;
  int wv = tid >> 6, lane = tid & 63;
  int quad = lane >> 4, l15 = lane & 15;
  int koff = quad * 8;

  // ---- P0: loads + zero-init ----
  if (tid < 2) s_cnt[tid] = 0;
  if (tid < 64) s_pool2[tid] = 0.f;
  if (tid < LV) s_sc[tid] = ws[WS_SCORE + ((size_t)t * BV + v) * LV + tid];
  {
    uint* za = (uint*)s_wa;
    for (int i = tid; i < 64 * WA_STR / 2; i += 512) za[i] = 0u;
    uint* zs = (uint*)(s_selh + 50 * SEL_STR);
    for (int i = tid; i < 14 * SEL_STR / 2; i += 512) zs[i] = 0u;
  }
  __syncthreads();

  // ---- P1: rank & partition ----
  if (tid < LV) {
    float my = s_sc[tid];
    int cnt = 0;
    for (int j = 0; j < LV; ++j) {
      float sj = s_sc[j];
      cnt += (sj > my) || (sj == my && j < tid);
    }
    bool keep = cnt < NKEEP;
    out[BV * BT + ((size_t)t * BV + v) * LV + tid] = keep ? 1.f : 0.f;
    if (keep) { int p = atomicAdd(&s_cnt[0], 1); s_kidx[p] = tid; }
    else      { int p = atomicAdd(&s_cnt[1], 1); s_nidx[p] = tid; }
  }
  __syncthreads();

  // ---- P2: softmax over non-kept scores -> s_wk ----
  if (tid < 128) s_red[tid] = (tid < NNON) ? s_sc[s_nidx[tid]] : -3.0e38f;
  __syncthreads();
  for (int off = 64; off > 0; off >>= 1) {
    if (tid < off) s_red[tid] = fmaxf(s_red[tid], s_red[tid + off]);
    __syncthreads();
  }
  float nm = s_red[0];
  __syncthreads();
  float e0 = 0.f;
  if (tid < NNON) e0 = expf(s_sc[s_nidx[tid]] - nm);
  if (tid < 128) s_red[tid] = (tid < NNON) ? e0 : 0.f;
  __syncthreads();
  for (int off = 64; off > 0; off >>= 1) {
    if (tid < off) s_red[tid] += s_red[tid + off];
    __syncthreads();
  }
  float nS = s_red[0];
  __syncthreads();
  if (tid < NNON) s_wk[tid] = e0 / nS;
  __syncthreads();

  // ---- P3: wlog gather -> s_w[p][r] fp32, softmax over r per pool ----
  float scale_val = scale_p[0];
  for (int i = tid; i < KEEPED * NKEEP; i += 512) {
    int k = i / KEEPED, p = i - k * KEEPED;
    s_w[p * NKEEP + k] = ws[WS_WLOG + ((size_t)v * LV + s_kidx[k]) * KEEPED + p] * scale_val;
  }
  __syncthreads();
  if (tid < KEEPED * 8) {
    int p = tid >> 3, g = tid & 7;
    float mm = -3e38f;
    for (int k = g; k < NKEEP; k += 8) mm = fmaxf(mm, s_w[p * NKEEP + k]);
    #pragma unroll
    for (int off = 4; off > 0; off >>= 1) mm = fmaxf(mm, __shfl_xor(mm, off, 8));
    float ss = 0.f;
    for (int k = g; k < NKEEP; k += 8) {
      float ee = expf(s_w[p * NKEEP + k] - mm);
      s_w[p * NKEEP + k] = ee;
      ss += ee;
    }
    #pragma unroll
    for (int off = 4; off > 0; off >>= 1) ss += __shfl_xor(ss, off, 8);
    float rs = 1.f / ss;
    for (int k = g; k < NKEEP; k += 8) s_w[p * NKEEP + k] *= rs;
  }
  __syncthreads();

  // ---- P4: scatter A = s_wa (bf16): kept weights + wk row 49 ----
  for (int i = tid; i < KEEPED * NKEEP; i += 512) {
    int p = i / NKEEP, r = i - p * NKEEP;
    s_wa[p * WA_STR + s_kidx[r]] = __float2bfloat16(s_w[p * NKEEP + r]);
  }
  if (tid < NNON) s_wa[49 * WA_STR + s_nidx[tid]] = __float2bfloat16(s_wk[tid]);
  __syncthreads();

  // ---- P5: aggr GEMM, K-loop of 7 x 32 tokens ----
  v4f acc[4][4];
  #pragma unroll
  for (int m = 0; m < 4; ++m)
    #pragma unroll
    for (int j = 0; j < 4; ++j) acc[m][j] = (v4f){0.f, 0.f, 0.f, 0.f};

  if (USE_IMGT) {
    const __hip_bfloat16* imgTv =
        (const __hip_bfloat16*)((const char*)ws + WS_IMGT_B) + (size_t)v * CDIM * TOKPAD;
    for (int ks = 0; ks < 7; ++ks) {
      v8s bfr[4];
      #pragma unroll
      for (int j = 0; j < 4; ++j)
        bfr[j] = *(const v8s*)(imgTv + (size_t)(wv * 64 + j * 16 + l15) * TOKPAD + ks * 32 + koff);
      #pragma unroll
      for (int m = 0; m < 4; ++m) {
        v8s af = *(const v8s*)(s_wa + (m * 16 + l15) * WA_STR + ks * 32 + koff);
        #pragma unroll
        for (int j = 0; j < 4; ++j) acc[m][j] = MFMA16(af, bfr[j], acc[m][j]);
      }
    }
  } else {
    for (int ks = 0; ks < 7; ++ks) {
      #pragma unroll
      for (int it = 0; it < 8; ++it) {
        int k0 = ks * 32 + it * 4;
        if (k0 < LV) {
          const float* gp = img + ((size_t)v * LV + k0) * CDIM + tid;
          float x0 = gp[0], x1 = gp[CDIM], x2 = gp[2 * CDIM], x3 = gp[3 * CDIM];
          union { __hip_bfloat16 h[4]; uint2 u; } pk;
          pk.h[0] = __float2bfloat16(x0); pk.h[1] = __float2bfloat16(x1);
          pk.h[2] = __float2bfloat16(x2); pk.h[3] = __float2bfloat16(x3);
          *(uint2*)(s_tok + tid * TOK_STR + it * 4) = pk.u;
        }
      }
      __syncthreads();
      v8s bfr[4];
      #pragma unroll
      for (int j = 0; j < 4; ++j)
        bfr[j] = *(const v8s*)(s_tok + (wv * 64 + j * 16 + l15) * TOK_STR + koff);
      #pragma unroll
      for (int m = 0; m < 4; ++m) {
        v8s af = *(const v8s*)(s_wa + (m * 16 + l15) * WA_STR + ks * 32 + koff);
        #pragma unroll
        for (int j = 0; j < 4; ++j) acc[m][j] = MFMA16(af, bfr[j], acc[m][j]);
      }
      __syncthreads();
    }
  }

  // ---- P6: cap staging (s_dyn free now) + pool l2norm ----
  if (!USE_IMGT) __syncthreads();
  for (int i = tid; i < NW * 128; i += 512) {
    int w = i >> 7, cq = i & 127;
    const float4 xv = *(const float4*)(ws + WS_CAPNORM + ((size_t)t * NW + w) * CDIM + cq * 4);
    union { __hip_bfloat16 h[4]; uint2 u; } pk;
    pk.h[0] = __float2bfloat16(xv.x); pk.h[1] = __float2bfloat16(xv.y);
    pk.h[2] = __float2bfloat16(xv.z); pk.h[3] = __float2bfloat16(xv.w);
    *(uint2*)(s_cap + w * SEL_STR + cq * 4) = pk.u;
  }
  {
    uint* zc = (uint*)(s_cap + 24 * SEL_STR);
    for (int i = tid; i < 8 * SEL_STR / 2; i += 512) zc[i] = 0u;
  }
  #pragma unroll
  for (int m = 0; m < 4; ++m) {
    #pragma unroll
    for (int reg = 0; reg < 4; ++reg) {
      float ss = acc[m][0][reg] * acc[m][0][reg] + acc[m][1][reg] * acc[m][1][reg]
               + acc[m][2][reg] * acc[m][2][reg] + acc[m][3][reg] * acc[m][3][reg];
      #pragma unroll
      for (int off = 8; off > 0; off >>= 1) ss += __shfl_xor(ss, off, 64);
      if (l15 == 0) atomicAdd(&s_pool2[m * 16 + quad * 4 + reg], ss);
    }
  }
  __syncthreads();
  if (tid < 64) s_inv[tid] = 1.f / fmaxf(sqrtf(s_pool2[tid]), 1e-12f);
  __syncthreads();
  #pragma unroll
  for (int m = 0; m < 4; ++m) {
    #pragma unroll
    for (int reg = 0; reg < 4; ++reg) {
      int p = m * 16 + quad * 4 + reg;
      if (p < 50) {
        float iv = s_inv[p];
        #pragma unroll
        for (int j = 0; j < 4; ++j)
          s_selh[p * SEL_STR + wv * 64 + j * 16 + l15] = __float2bfloat16(acc[m][j][reg] * iv);
      }
    }
  }
  __syncthreads();

  // ---- P7: sims = cap . sel^T via MFMA ----
  {
    int mt = wv >> 2, nt = wv & 3;
    v4f sa = (v4f){0.f, 0.f, 0.f, 0.f};
    for (int ks = 0; ks < 16; ++ks) {
      v8s a = *(const v8s*)(s_cap + (mt * 16 + l15) * SEL_STR + ks * 32 + koff);
      v8s bb = *(const v8s*)(s_selh + (nt * 16 + l15) * SEL_STR + ks * 32 + koff);
      sa = MFMA16(a, bb, sa);
    }
    #pragma unroll
    for (int reg = 0; reg < 4; ++reg)
      s_sims[(mt * 16 + quad * 4 + reg) * 64 + nt * 16 + l15] = sa[reg];
  }
  __syncthreads();

  // ---- P8: per-word softmax (unnormalized e) + num = sum e*s ----
  if (tid < NW * 8) {
    int w = tid >> 3, g = tid & 7;
    float* row = s_sims + w * 64;
    float mm = -3e38f;
    for (int p = g; p < 50; p += 8) mm = fmaxf(mm, row[p]);
    #pragma unroll
    for (int off = 4; off > 0; off >>= 1) mm = fmaxf(mm, __shfl_xor(mm, off, 8));
    float num = 0.f;
    for (int p = g; p < 64; p += 8) {
      if (p < 50) {
        float s = row[p];
        float ee = expf(LAMBDA_ * (s - mm));
        num += ee * s;
        row[p] = ee;
      } else row[p] = 0.f;
    }
    #pragma unroll
    for (int off = 4; off > 0; off >>= 1) num += __shfl_xor(num, off, 8);
    if (g == 0) s_red[w] = num;
  }
  __syncthreads();

  // ---- P9: G = sel . sel^T via MFMA ----
  #pragma unroll
  for (int i2 = 0; i2 < 2; ++i2) {
    int idx = wv * 2 + i2;
    int gm = idx >> 2, gn = idx & 3;
    v4f ga = (v4f){0.f, 0.f, 0.f, 0.f};
    for (int ks = 0; ks < 16; ++ks) {
      v8s a = *(const v8s*)(s_selh + (gm * 16 + l15) * SEL_STR + ks * 32 + koff);
      v8s bb = *(const v8s*)(s_selh + (gn * 16 + l15) * SEL_STR + ks * 32 + koff);
      ga = MFMA16(a, bb, ga);
    }
    #pragma unroll
    for (int reg = 0; reg < 4; ++reg)
      s_G[(gm * 16 + quad * 4 + reg) * G_STR + gn * 16 + l15] = ga[reg];
  }
  __syncthreads();

  // ---- P10: word_sim = num / sqrt(e^T G e); mean over words ----
  float wacc = 0.f;
  for (int w = wv; w < NW; w += 8) {
    const float* ev = s_sims + w * 64;
    float tl = 0.f;
    for (int q = 0; q < 50; ++q) tl += s_G[q * G_STR + lane] * ev[q];
    float ql = ev[lane] * tl;
    #pragma unroll
    for (int off = 32; off > 0; off >>= 1) ql += __shfl_xor(ql, off, 64);
    if (lane == 0) wacc += s_red[w] / fmaxf(sqrtf(ql), 1e-20f);
  }
  if (lane == 0) s_red[64 + wv] = wacc;
  __syncthreads();
  if (tid == 0) {
    float s = 0.f;
    #pragma unroll
    for (int i = 0; i < 8; ++i) s += s_red[64 + i];
    out[(size_t)v * BT + t] = s / (float)NW;
  }
}

// ---------------------------------------------------------------------------
extern "C" void kernel_launch(void* const* d_in, const int* in_sizes, int n_in,
                              void* d_out, int out_size, void* d_ws, size_t ws_size,
                              hipStream_t stream) {
  const float* img   = (const float*)d_in[0];
  const float* cap   = (const float*)d_in[1];
  // d_in[2] = cap_lens (unused by forward)
  const float* gamma = (const float*)d_in[3];
  const float* beta  = (const float*)d_in[4];
  const float* W1    = (const float*)d_in[5];
  const float* b1    = (const float*)d_in[6];
  const float* W2    = (const float*)d_in[7];
  const float* b2    = (const float*)d_in[8];
  const float* scale = (const float*)d_in[9];
  float* ws  = (float*)d_ws;
  float* out = (float*)d_out;

  const bool big = (ws_size >= WS_NEED_B);   // constant across calls -> graph-safe

  if (big) k0_prep<<<dim3(BV, 7), dim3(512), 0, stream>>>(img, ws);
  k5_prep<<<dim3(176), dim3(512), 0, stream>>>(W1, W2, ws);
  k1_glo <<<dim3(BT + BV), dim3(256), 0, stream>>>(img, cap, ws);
  k2_mlp <<<dim3(BV, 2), dim3(512), 0, stream>>>(img, gamma, beta, b1, b2, ws);
  k3_score<<<dim3(BV, 4), dim3(256), 0, stream>>>(img, ws);
  if (big) k4_main<1><<<dim3(BV * BT), dim3(512), 0, stream>>>(img, scale, ws, out);
  else     k4_main<0><<<dim3(BV * BT), dim3(512), 0, stream>>>(img, scale, ws, out);
}